// Round 3
// baseline (893.180 us; speedup 1.0000x reference)
//
#include <hip/hip_runtime.h>
#include <hip/hip_bf16.h>

// Problem constants
#define NB 8
#define N1S 64
#define N2S 512
#define DD 128
#define HH 128
#define NT 7
#define LCAP 4096   // per-(b,t) list capacity

__device__ __constant__ float BCON[NT] = {1.159f,0.448f,0.927f,0.902f,0.349f,0.789f,0.198f};

// ---------------- embed: out[row,:] = x[row,:56] @ W[56,128] ----------------
// One launch for both inputs: rows [0,512) -> h1, [512,5120) -> h2.
__global__ __launch_bounds__(128) void k_embed(const float* __restrict__ x1,
                                               const float* __restrict__ x2,
                                               const float* __restrict__ W,
                                               float* __restrict__ o1,
                                               float* __restrict__ o2) {
  int row = blockIdx.x; int d = threadIdx.x;
  const float* x; float* out;
  if (row < NB*N1S) { x = x1 + (size_t)row*56;            out = o1 + (size_t)row*DD; }
  else              { x = x2 + (size_t)(row-NB*N1S)*56;   out = o2 + (size_t)(row-NB*N1S)*DD; }
  __shared__ float xs[64];
  if (d < 56) xs[d] = x[d];
  __syncthreads();
  float acc = 0.f;
  for (int k = 0; k < 56; ++k) acc += xs[k] * W[k*DD + d];
  out[d] = acc;
}

// ---- tiled GEMM  C = A @ B (+bias), K=128, two row-sources in one launch ----
// grid: (x = 4 col-tiles, y = split + M2/32 row-tiles). bias indexed by col.
__global__ __launch_bounds__(256) void k_gemm128(
    const float* __restrict__ A1, const float* __restrict__ A2, int split,
    const float* __restrict__ Bw, const float* __restrict__ bias,
    float* __restrict__ C1, float* __restrict__ C2)
{
  int yb = blockIdx.y;
  const float* A; float* C; int row0;
  if (yb < split) { A = A1; C = C1; row0 = yb*32; }
  else            { A = A2; C = C2; row0 = (yb-split)*32; }
  int j0 = blockIdx.x*32;
  __shared__ float As[32][36], Bs[32][36];   // pad 36 keeps float4 LDS ops 16B-aligned
  int t = threadIdx.x;
  int lr = t >> 3, lc = t & 7;     // loader: row, float4-col
  int ti = t >> 3, tj4 = t & 7;    // compute: row, 4-col group
  float acc[4] = {0.f,0.f,0.f,0.f};
  for (int kc = 0; kc < 128; kc += 32) {
    float4 av = *(const float4*)(A  + (size_t)(row0+lr)*128 + kc + lc*4);
    float4 bv = *(const float4*)(Bw + (size_t)(kc+lr)*128 + j0 + lc*4);
    *(float4*)&As[lr][lc*4] = av;   // As[row][k]
    *(float4*)&Bs[lr][lc*4] = bv;   // Bs[k][j]
    __syncthreads();
    for (int kk = 0; kk < 32; ++kk) {
      float a = As[ti][kk];
      float4 b4 = *(const float4*)&Bs[kk][tj4*4];
      acc[0] += a*b4.x; acc[1] += a*b4.y; acc[2] += a*b4.z; acc[3] += a*b4.w;
    }
    __syncthreads();
  }
  if (bias) {
    const float* bp = bias + j0 + tj4*4;
    acc[0] += bp[0]; acc[1] += bp[1]; acc[2] += bp[2]; acc[3] += bp[3];
  }
  *(float4*)(C + (size_t)(row0+ti)*128 + j0 + tj4*4) = make_float4(acc[0],acc[1],acc[2],acc[3]);
}

// ---- U-precompute: all 14 (type,mlp) first-layer GEMMs in one launch ----
// grid (4, 144, 14): y<16 -> c1 rows (top W1 half, bias folded), else c2 rows
// (bottom W1 half, no bias). z<7 -> A-MLP type z, else B-MLP type z-7.
__global__ __launch_bounds__(256) void k_ugemm(
    const float* __restrict__ c1, const float* __restrict__ c2,
    const float* __restrict__ WA1, const float* __restrict__ bA1,
    const float* __restrict__ WB1, const float* __restrict__ bB1,
    float* __restrict__ U1A, float* __restrict__ U2A,
    float* __restrict__ U1B, float* __restrict__ U2B)
{
  int z = blockIdx.z;
  int t7 = (z < 7) ? z : z - 7;
  const float* W1 = (z < 7 ? WA1 : WB1) + (size_t)t7*2*DD*HH;
  int yb = blockIdx.y;
  const float* A; float* C; int row0; const float* bias;
  if (yb < 16) {
    A = c1; row0 = yb*32;
    C = (z < 7 ? U1A : U1B) + (size_t)t7*NB*N1S*DD;
    bias = (z < 7 ? bA1 : bB1) + t7*HH;
  } else {
    A = c2; row0 = (yb-16)*32;
    C = (z < 7 ? U2A : U2B) + (size_t)t7*NB*N2S*DD;
    W1 += DD*HH;
    bias = nullptr;
  }
  int j0 = blockIdx.x*32;
  __shared__ float As[32][36], Bs[32][36];
  int t = threadIdx.x;
  int lr = t >> 3, lc = t & 7;
  int ti = t >> 3, tj4 = t & 7;
  float acc[4] = {0.f,0.f,0.f,0.f};
  for (int kc = 0; kc < 128; kc += 32) {
    float4 av = *(const float4*)(A  + (size_t)(row0+lr)*128 + kc + lc*4);
    float4 bv = *(const float4*)(W1 + (size_t)(kc+lr)*128 + j0 + lc*4);
    *(float4*)&As[lr][lc*4] = av;
    *(float4*)&Bs[lr][lc*4] = bv;
    __syncthreads();
    for (int kk = 0; kk < 32; ++kk) {
      float a = As[ti][kk];
      float4 b4 = *(const float4*)&Bs[kk][tj4*4];
      acc[0] += a*b4.x; acc[1] += a*b4.y; acc[2] += a*b4.z; acc[3] += a*b4.w;
    }
    __syncthreads();
  }
  if (bias) {
    const float* bp = bias + j0 + tj4*4;
    acc[0] += bp[0]; acc[1] += bp[1]; acc[2] += bp[2]; acc[3] += bp[3];
  }
  *(float4*)(C + (size_t)(row0+ti)*128 + j0 + tj4*4) = make_float4(acc[0],acc[1],acc[2],acc[3]);
}

// ---- e[b,i,j] = hA[b,i,:] . h[b,j,:]  (both sets in one launch) ----
// grid (16, 18, 8): y<16 -> set2 tile, y in [16,18) & x<2 -> set1 tile.
__global__ __launch_bounds__(256) void k_egemm(
    const float* __restrict__ hA2, const float* __restrict__ h2v, float* __restrict__ e2,
    const float* __restrict__ hA1, const float* __restrict__ h1v, float* __restrict__ e1)
{
  int b = blockIdx.z;
  int N, i0, j0; const float *Ap, *Hp; float* ep;
  if (blockIdx.y < 16) {
    N = N2S; i0 = blockIdx.y*32; j0 = blockIdx.x*32;
    Ap = hA2 + (size_t)b*N*DD; Hp = h2v + (size_t)b*N*DD; ep = e2 + (size_t)b*N*N;
  } else {
    if (blockIdx.x >= 2) return;
    N = N1S; i0 = (blockIdx.y-16)*32; j0 = blockIdx.x*32;
    Ap = hA1 + (size_t)b*N*DD; Hp = h1v + (size_t)b*N*DD; ep = e1 + (size_t)b*N*N;
  }
  __shared__ float As[32][36], Bs[32][36];  // Bs transposed: Bs[k][j]
  int t = threadIdx.x;
  int lr = t >> 3, lc = t & 7;
  int ti = t >> 3, tj4 = t & 7;
  float acc[4] = {0.f,0.f,0.f,0.f};
  for (int kc = 0; kc < DD; kc += 32) {
    float4 av = *(const float4*)(Ap + (size_t)(i0+lr)*DD + kc + lc*4);
    float4 bv = *(const float4*)(Hp + (size_t)(j0+lr)*DD + kc + lc*4);
    *(float4*)&As[lr][lc*4] = av;
    Bs[lc*4+0][lr] = bv.x;   // 2-way bank aliasing on store: free (m136)
    Bs[lc*4+1][lr] = bv.y;
    Bs[lc*4+2][lr] = bv.z;
    Bs[lc*4+3][lr] = bv.w;
    __syncthreads();
    for (int kk = 0; kk < 32; ++kk) {
      float a = As[ti][kk];
      float4 b4 = *(const float4*)&Bs[kk][tj4*4];
      acc[0] += a*b4.x; acc[1] += a*b4.y; acc[2] += a*b4.z; acc[3] += a*b4.w;
    }
    __syncthreads();
  }
  *(float4*)(ep + (size_t)(i0+ti)*N + j0 + tj4*4) = make_float4(acc[0],acc[1],acc[2],acc[3]);
}

// ---- column softmax stats over axis i (both sets): m_j, s_j of masked esym ----
// grid (9, NB): x<8 -> set2 col-block, x==8 -> set1 (all 64 cols).
__global__ __launch_bounds__(256) void k_stats(
    const float* __restrict__ e2, const float* __restrict__ adj2,
    float* __restrict__ m2, float* __restrict__ s2v,
    const float* __restrict__ e1, const float* __restrict__ adj1,
    float* __restrict__ m1, float* __restrict__ s1v)
{
  int b = blockIdx.y;
  int tj = threadIdx.x & 63, ti = threadIdx.x >> 6;
  int N, j; const float *ep, *ap; float *ms, *ss;
  if (blockIdx.x < 8) {
    N = N2S; j = blockIdx.x*64 + tj;
    ep = e2 + (size_t)b*N*N; ap = adj2 + (size_t)b*N*N;
    ms = m2 + (size_t)b*N;   ss = s2v + (size_t)b*N;
  } else {
    N = N1S; j = tj;
    ep = e1 + (size_t)b*N*N; ap = adj1 + (size_t)b*N*N;
    ms = m1 + (size_t)b*N;   ss = s1v + (size_t)b*N;
  }
  float m = -3.0e38f, s = 0.f;
  for (int i = ti; i < N; i += 4) {
    float av = ap[(size_t)i*N + j];
    float v = (av > 0.f) ? (ep[(size_t)i*N + j] + ep[(size_t)j*N + i]) : -9e15f;
    float nm = fmaxf(m, v);
    s = s*__expf(m - nm) + __expf(v - nm);
    m = nm;
  }
  __shared__ float lm[4][64], ls[4][64];
  lm[ti][tj] = m; ls[ti][tj] = s;
  __syncthreads();
  if (ti == 0) {
    float M = lm[0][tj];
    for (int c = 1; c < 4; ++c) M = fmaxf(M, lm[c][tj]);
    float S = 0.f;
    for (int c = 0; c < 4; ++c) S += ls[c][tj]*__expf(lm[c][tj] - M);
    ms[j] = M;
    ss[j] = S;
  }
}

// ---- hp + gate + blend, both sets: grid (144, NB), 128 thr, 4 rows/block ----
__global__ __launch_bounds__(128) void k_hp(
    const float* __restrict__ e2, const float* __restrict__ adj2,
    const float* __restrict__ m2, const float* __restrict__ s2v,
    const float* __restrict__ hb2, const float* __restrict__ x2, float* __restrict__ o2,
    const float* __restrict__ e1, const float* __restrict__ adj1,
    const float* __restrict__ m1, const float* __restrict__ s1v,
    const float* __restrict__ hb1, const float* __restrict__ x1, float* __restrict__ o1,
    const float* __restrict__ Wg, const float* __restrict__ bg)
{
  int b = blockIdx.y; int d = threadIdx.x;
  int N, i0; const float *ep, *ap, *msb, *ssb, *hb, *x; float* out;
  if (blockIdx.x < 128) {
    N = N2S; i0 = blockIdx.x*4;
    ep = e2 + (size_t)b*N*N; ap = adj2 + (size_t)b*N*N;
    msb = m2 + (size_t)b*N;  ssb = s2v + (size_t)b*N;
    hb = hb2 + (size_t)b*N*DD; x = x2 + (size_t)b*N*DD; out = o2 + (size_t)b*N*DD;
  } else {
    N = N1S; i0 = (blockIdx.x-128)*4;
    ep = e1 + (size_t)b*N*N; ap = adj1 + (size_t)b*N*N;
    msb = m1 + (size_t)b*N;  ssb = s1v + (size_t)b*N;
    hb = hb1 + (size_t)b*N*DD; x = x1 + (size_t)b*N*DD; out = o1 + (size_t)b*N*DD;
  }
  __shared__ float ps[4][DD];
  __shared__ float red[DD];
  float hp[4] = {0.f,0.f,0.f,0.f};
  for (int j0 = 0; j0 < N; j0 += DD) {
    int j = j0 + d;
    if (j < N) {
      float mj = msb[j], sj = ssb[j];
      for (int r = 0; r < 4; ++r) {
        int i = i0 + r;
        float av = ap[(size_t)i*N + j];
        float p = 0.f;
        if (av > 0.f)
          p = __expf(ep[(size_t)i*N + j] + ep[(size_t)j*N + i] - mj) / sj;
        ps[r][d] = p;
      }
    } else {
      for (int r = 0; r < 4; ++r) ps[r][d] = 0.f;
    }
    __syncthreads();
    int jmax = min(DD, N - j0);
    for (int jj = 0; jj < jmax; ++jj) {
      float hv = hb[(size_t)(j0+jj)*DD + d];
      hp[0] += ps[0][jj]*hv;
      hp[1] += ps[1][jj]*hv;
      hp[2] += ps[2][jj]*hv;
      hp[3] += ps[3][jj]*hv;
    }
    __syncthreads();
  }
  for (int r = 0; r < 4; ++r) {
    int i = i0 + r;
    float hpr = fmaxf(hp[r], 0.f);
    float xv = x[(size_t)i*DD + d];
    red[d] = xv*Wg[d] + hpr*Wg[DD + d];
    __syncthreads();
    for (int s2 = 64; s2 > 0; s2 >>= 1) {
      if (d < s2) red[d] += red[d + s2];
      __syncthreads();
    }
    float coeff = 1.f/(1.f + __expf(-(red[0] + bg[0])));
    out[(size_t)i*DD + d] = coeff*xv + (1.f - coeff)*hpr;
    __syncthreads();
  }
}

// ------- build active (i1,i2) lists per (b,t); one atomic per wave -------
__global__ __launch_bounds__(256) void k_build(const float* __restrict__ A_int,
                                               int* __restrict__ counts,
                                               int* __restrict__ lists) {
  int idx = blockIdx.x*256 + threadIdx.x;
  bool active = (A_int[idx] != 0.f);
  unsigned long long mask = __ballot(active);
  int lane = threadIdx.x & 63;
  int bt = idx >> 15;              // 32768 pairs per (b,t); wave-uniform
  int before = __popcll(mask & ((1ull << lane) - 1ull));
  int n = __popcll(mask);
  int base = 0;
  if (lane == 0 && n) base = atomicAdd(&counts[bt], n);
  base = __shfl(base, 0);
  if (active) {
    int pos = base + before;
    if (pos < LCAP) lists[bt*LCAP + pos] = idx & 32767;  // (i1<<9)|i2
  }
}

// ------- sparse pair phase: hid = relu(U1[i1]+U2[i2]); sig(hid.W2+b2) -------
__global__ __launch_bounds__(256) void k_pair(
    const float* __restrict__ U1A, const float* __restrict__ U2A,
    const float* __restrict__ U1B, const float* __restrict__ U2B,
    const float* __restrict__ WA2, const float* __restrict__ bA2,
    const float* __restrict__ WB2, const float* __restrict__ bB2,
    const float* __restrict__ dmv, const float* __restrict__ Cv,
    const int* __restrict__ lists, const int* __restrict__ counts,
    float* __restrict__ retval)
{
  int bt = blockIdx.y; int b = bt / NT, t = bt % NT;
  int cnt = min(counts[bt], LCAP);
  __shared__ __align__(16) float w2a[HH], w2b[HH];
  int tid = threadIdx.x;
  if (tid < HH) w2a[tid] = WA2[t*HH + tid];
  else          w2b[tid-HH] = WB2[t*HH + tid - HH];
  __syncthreads();
  int lane = tid & 63, w = tid >> 6;
  float bcv = BCON[t];
  float bcinv = 1.f/(3.f*bcv*bcv);
  float b2a = bA2[t], b2b = bB2[t], c = Cv[t];
  const float* u1a = U1A + (size_t)t*NB*N1S*DD + (size_t)b*N1S*DD;
  const float* u2a = U2A + (size_t)t*NB*N2S*DD + (size_t)b*N2S*DD;
  const float* u1b = U1B + (size_t)t*NB*N1S*DD + (size_t)b*N1S*DD;
  const float* u2b = U2B + (size_t)t*NB*N2S*DD + (size_t)b*N2S*DD;
  float2 wva = ((const float2*)w2a)[lane];
  float2 wvb = ((const float2*)w2b)[lane];
  float acc = 0.f;
  for (int p = blockIdx.x*4 + w; p < cnt; p += gridDim.x*4) {
    int id = lists[bt*LCAP + p];
    int i1 = id >> 9, i2 = id & 511;
    float2 a1 = ((const float2*)(u1a + (size_t)i1*DD))[lane];
    float2 a2 = ((const float2*)(u2a + (size_t)i2*DD))[lane];
    float2 b1 = ((const float2*)(u1b + (size_t)i1*DD))[lane];
    float2 b2 = ((const float2*)(u2b + (size_t)i2*DD))[lane];
    float pA = fmaxf(a1.x + a2.x, 0.f)*wva.x + fmaxf(a1.y + a2.y, 0.f)*wva.y;
    float pB = fmaxf(b1.x + b2.x, 0.f)*wvb.x + fmaxf(b1.y + b2.y, 0.f)*wvb.y;
    for (int off = 32; off; off >>= 1) {
      pA += __shfl_xor(pA, off);
      pB += __shfl_xor(pB, off);
    }
    float Aval = 4.f/(1.f + __expf(-(pA + b2a)));
    float Bval = (2.f*bcinv)/(1.f + __expf(-(pB + b2b))) + bcinv;
    const float* dp = dmv + (((size_t)b*N1S + i1)*N2S + i2)*3;
    float dx = dp[0], dy = dp[1], dz = dp[2];
    float dm = sqrtf(dx*dx + dy*dy + dz*dz + 1e-10f);
    if (dm < 0.5f) dm = 1e10f;
    float diff = dm - c;
    float ev = Aval*(Bval*diff*diff - 1.f);
    if (lane == 0) acc += ev;
  }
  __shared__ float wsum[4];
  if (lane == 0) wsum[w] = acc;
  __syncthreads();
  if (tid == 0)
    atomicAdd(&retval[bt], wsum[0]+wsum[1]+wsum[2]+wsum[3]);
}

// ---------------- pooled intercept + final output ----------------
__global__ __launch_bounds__(128) void k_intercept(const float* __restrict__ h1e,
                                                   const float* __restrict__ valid,
                                                   const float* __restrict__ Wi1,
                                                   const float* __restrict__ bi1,
                                                   const float* __restrict__ Wi2,
                                                   const float* __restrict__ bi2,
                                                   const float* __restrict__ retval,
                                                   float* __restrict__ out) {
  int b = blockIdx.x; int d = threadIdx.x;
  __shared__ float pooled[DD], hid[DD], red[DD];
  float s = 0.f;
  for (int i = 0; i < N1S; ++i)
    s += h1e[((size_t)b*N1S + i)*DD + d] * valid[b*N1S + i];
  pooled[d] = s;
  __syncthreads();
  float a = bi1[d];
  for (int k = 0; k < DD; ++k) a += pooled[k]*Wi1[k*HH + d];
  hid[d] = fmaxf(a, 0.f);
  __syncthreads();
  red[d] = hid[d]*Wi2[d];
  __syncthreads();
  for (int s2 = 64; s2 > 0; s2 >>= 1) {
    if (d < s2) red[d] += red[d + s2];
    __syncthreads();
  }
  float inter = 4.f/(1.f + __expf(-(red[0] + bi2[0])));
  if (d < NT) out[b*NT + d] = retval[b*NT + d] + inter/(float)NT;
}

extern "C" void kernel_launch(void* const* d_in, const int* in_sizes, int n_in,
                              void* d_out, int out_size, void* d_ws, size_t ws_size,
                              hipStream_t stream) {
  (void)in_sizes; (void)n_in; (void)out_size; (void)ws_size;
  const float* h1     = (const float*)d_in[0];
  const float* adj1   = (const float*)d_in[1];
  const float* h2     = (const float*)d_in[2];
  const float* adj2   = (const float*)d_in[3];
  const float* A_int  = (const float*)d_in[4];
  const float* dmv    = (const float*)d_in[5];
  const float* valid  = (const float*)d_in[6];
  const float* W_embed= (const float*)d_in[7];
  const float* gW     = (const float*)d_in[8];
  const float* gWb    = (const float*)d_in[9];
  const float* gA     = (const float*)d_in[10];
  const float* gGateW = (const float*)d_in[11];
  const float* gGateb = (const float*)d_in[12];
  const float* WA1    = (const float*)d_in[13];
  const float* bA1    = (const float*)d_in[14];
  const float* WA2    = (const float*)d_in[15];
  const float* bA2    = (const float*)d_in[16];
  const float* WB1    = (const float*)d_in[17];
  const float* bB1    = (const float*)d_in[18];
  const float* WB2    = (const float*)d_in[19];
  const float* bB2    = (const float*)d_in[20];
  const float* Cv     = (const float*)d_in[21];
  const float* Wi1    = (const float*)d_in[22];
  const float* bi1    = (const float*)d_in[23];
  const float* Wi2    = (const float*)d_in[24];
  const float* bi2    = (const float*)d_in[25];

  float* base = (float*)d_ws;
  size_t off = 0;
  auto alloc = [&](size_t n) { float* p = base + off; off += n; return p; };
  float* h1a   = alloc((size_t)NB*N1S*DD);
  float* h1b   = alloc((size_t)NB*N1S*DD);
  float* h2a   = alloc((size_t)NB*N2S*DD);
  float* h2b   = alloc((size_t)NB*N2S*DD);
  float* hb1   = alloc((size_t)NB*N1S*DD);
  float* hAb1  = alloc((size_t)NB*N1S*DD);
  float* hb2   = alloc((size_t)NB*N2S*DD);
  float* hAb2  = alloc((size_t)NB*N2S*DD);
  float* e1    = alloc((size_t)NB*N1S*N1S);
  float* e2    = alloc((size_t)NB*N2S*N2S);
  float* m1    = alloc((size_t)NB*N1S);
  float* s1    = alloc((size_t)NB*N1S);
  float* m2    = alloc((size_t)NB*N2S);
  float* s2    = alloc((size_t)NB*N2S);
  float* U1A   = alloc((size_t)NT*NB*N1S*DD);
  float* U2A   = alloc((size_t)NT*NB*N2S*DD);
  float* U1B   = alloc((size_t)NT*NB*N1S*DD);
  float* U2B   = alloc((size_t)NT*NB*N2S*DD);
  float* retval= alloc(NB*NT);
  int*   counts= (int*)alloc(NB*NT);
  int*   lists = (int*)alloc((size_t)NB*NT*LCAP);

  hipMemsetAsync(retval, 0, NB*NT*sizeof(float), stream);
  hipMemsetAsync(counts, 0, NB*NT*sizeof(int), stream);

  // sparse list build (independent of GAT chain)
  k_build<<<dim3((NB*NT*N1S*N2S)/256), 256, 0, stream>>>(A_int, counts, lists);

  k_embed<<<dim3(NB*(N1S+N2S)), 128, 0, stream>>>(h1, h2, W_embed, h1a, h2a);

  float* c1 = h1a; float* o1 = h1b;
  float* c2 = h2a; float* o2 = h2b;
  for (int l = 0; l < 3; ++l) {
    const float* W  = gW + (size_t)l*DD*DD;
    const float* Wb = gWb + (size_t)l*DD;
    const float* A  = gA + (size_t)l*DD*DD;
    const float* Wg = gGateW + (size_t)l*2*DD;
    const float* bg = gGateb + l;
    k_gemm128<<<dim3(4, 144), 256, 0, stream>>>(c1, c2, 16, W, Wb, hb1, hb2);
    k_gemm128<<<dim3(4, 144), 256, 0, stream>>>(hb1, hb2, 16, A, nullptr, hAb1, hAb2);
    k_egemm<<<dim3(16, 18, NB), 256, 0, stream>>>(hAb2, hb2, e2, hAb1, hb1, e1);
    k_stats<<<dim3(9, NB), 256, 0, stream>>>(e2, adj2, m2, s2, e1, adj1, m1, s1);
    k_hp<<<dim3(144, NB), 128, 0, stream>>>(e2, adj2, m2, s2, hb2, c2, o2,
                                            e1, adj1, m1, s1, hb1, c1, o1, Wg, bg);
    float* tmp;
    tmp = c1; c1 = o1; o1 = tmp;
    tmp = c2; c2 = o2; o2 = tmp;
  }

  // U1 = h1e @ W1_top (+b1); U2 = h2e @ W1_bot  — all 14 (t,mlp) in one launch
  k_ugemm<<<dim3(4, 144, 14), 256, 0, stream>>>(c1, c2, WA1, bA1, WB1, bB1,
                                                U1A, U2A, U1B, U2B);
  k_pair<<<dim3(32, NB*NT), 256, 0, stream>>>(U1A, U2A, U1B, U2B,
      WA2, bA2, WB2, bB2, dmv, Cv, lists, counts, retval);

  k_intercept<<<dim3(NB), 128, 0, stream>>>(c1, valid, Wi1, bi1, Wi2, bi2, retval,
                                            (float*)d_out);
}

// Round 4
// 689.281 us; speedup vs baseline: 1.2958x; 1.2958x over previous
//
#include <hip/hip_runtime.h>
#include <hip/hip_bf16.h>

// Problem constants
#define NB 8
#define N1S 64
#define N2S 512
#define DD 128
#define HH 128
#define NT 7
#define LCAP 4096   // per-(b,t) list capacity
#define CSTR 16     // counts[] stride in ints (64B cache line) to kill atomic line contention

__device__ __constant__ float BCON[NT] = {1.159f,0.448f,0.927f,0.902f,0.349f,0.789f,0.198f};

// ---------------- embed: out[row,:] = x[row,:56] @ W[56,128] ----------------
__global__ __launch_bounds__(128) void k_embed(const float* __restrict__ x1,
                                               const float* __restrict__ x2,
                                               const float* __restrict__ W,
                                               float* __restrict__ o1,
                                               float* __restrict__ o2) {
  int row = blockIdx.x; int d = threadIdx.x;
  const float* x; float* out;
  if (row < NB*N1S) { x = x1 + (size_t)row*56;            out = o1 + (size_t)row*DD; }
  else              { x = x2 + (size_t)(row-NB*N1S)*56;   out = o2 + (size_t)(row-NB*N1S)*DD; }
  __shared__ float xs[64];
  if (d < 56) xs[d] = x[d];
  __syncthreads();
  float acc = 0.f;
  for (int k = 0; k < 56; ++k) acc += xs[k] * W[k*DD + d];
  out[d] = acc;
}

// ---- tiled GEMM  C = A @ B (+bias), K=128, two row-sources in one launch ----
__global__ __launch_bounds__(256) void k_gemm128(
    const float* __restrict__ A1, const float* __restrict__ A2, int split,
    const float* __restrict__ Bw, const float* __restrict__ bias,
    float* __restrict__ C1, float* __restrict__ C2)
{
  int yb = blockIdx.y;
  const float* A; float* C; int row0;
  if (yb < split) { A = A1; C = C1; row0 = yb*32; }
  else            { A = A2; C = C2; row0 = (yb-split)*32; }
  int j0 = blockIdx.x*32;
  __shared__ float As[32][36], Bs[32][36];   // pad 36 keeps float4 LDS ops 16B-aligned
  int t = threadIdx.x;
  int lr = t >> 3, lc = t & 7;
  int ti = t >> 3, tj4 = t & 7;
  float acc[4] = {0.f,0.f,0.f,0.f};
  for (int kc = 0; kc < 128; kc += 32) {
    float4 av = *(const float4*)(A  + (size_t)(row0+lr)*128 + kc + lc*4);
    float4 bv = *(const float4*)(Bw + (size_t)(kc+lr)*128 + j0 + lc*4);
    *(float4*)&As[lr][lc*4] = av;
    *(float4*)&Bs[lr][lc*4] = bv;
    __syncthreads();
    for (int kk = 0; kk < 32; ++kk) {
      float a = As[ti][kk];
      float4 b4 = *(const float4*)&Bs[kk][tj4*4];
      acc[0] += a*b4.x; acc[1] += a*b4.y; acc[2] += a*b4.z; acc[3] += a*b4.w;
    }
    __syncthreads();
  }
  if (bias) {
    const float* bp = bias + j0 + tj4*4;
    acc[0] += bp[0]; acc[1] += bp[1]; acc[2] += bp[2]; acc[3] += bp[3];
  }
  *(float4*)(C + (size_t)(row0+ti)*128 + j0 + tj4*4) = make_float4(acc[0],acc[1],acc[2],acc[3]);
}

// ---- U-precompute: all 14 (type,mlp) first-layer GEMMs in one launch ----
__global__ __launch_bounds__(256) void k_ugemm(
    const float* __restrict__ c1, const float* __restrict__ c2,
    const float* __restrict__ WA1, const float* __restrict__ bA1,
    const float* __restrict__ WB1, const float* __restrict__ bB1,
    float* __restrict__ U1A, float* __restrict__ U2A,
    float* __restrict__ U1B, float* __restrict__ U2B)
{
  int z = blockIdx.z;
  int t7 = (z < 7) ? z : z - 7;
  const float* W1 = (z < 7 ? WA1 : WB1) + (size_t)t7*2*DD*HH;
  int yb = blockIdx.y;
  const float* A; float* C; int row0; const float* bias;
  if (yb < 16) {
    A = c1; row0 = yb*32;
    C = (z < 7 ? U1A : U1B) + (size_t)t7*NB*N1S*DD;
    bias = (z < 7 ? bA1 : bB1) + t7*HH;
  } else {
    A = c2; row0 = (yb-16)*32;
    C = (z < 7 ? U2A : U2B) + (size_t)t7*NB*N2S*DD;
    W1 += DD*HH;
    bias = nullptr;
  }
  int j0 = blockIdx.x*32;
  __shared__ float As[32][36], Bs[32][36];
  int t = threadIdx.x;
  int lr = t >> 3, lc = t & 7;
  int ti = t >> 3, tj4 = t & 7;
  float acc[4] = {0.f,0.f,0.f,0.f};
  for (int kc = 0; kc < 128; kc += 32) {
    float4 av = *(const float4*)(A  + (size_t)(row0+lr)*128 + kc + lc*4);
    float4 bv = *(const float4*)(W1 + (size_t)(kc+lr)*128 + j0 + lc*4);
    *(float4*)&As[lr][lc*4] = av;
    *(float4*)&Bs[lr][lc*4] = bv;
    __syncthreads();
    for (int kk = 0; kk < 32; ++kk) {
      float a = As[ti][kk];
      float4 b4 = *(const float4*)&Bs[kk][tj4*4];
      acc[0] += a*b4.x; acc[1] += a*b4.y; acc[2] += a*b4.z; acc[3] += a*b4.w;
    }
    __syncthreads();
  }
  if (bias) {
    const float* bp = bias + j0 + tj4*4;
    acc[0] += bp[0]; acc[1] += bp[1]; acc[2] += bp[2]; acc[3] += bp[3];
  }
  *(float4*)(C + (size_t)(row0+ti)*128 + j0 + tj4*4) = make_float4(acc[0],acc[1],acc[2],acc[3]);
}

// ---- esym[b,i,j] = hA[i].h[j] + h[i].hA[j]  (symmetric; both sets) ----
// Storing e+e^T directly kills all strided e[j*N+i] reads downstream.
__global__ __launch_bounds__(256) void k_egemm(
    const float* __restrict__ hA2, const float* __restrict__ h2v, float* __restrict__ e2,
    const float* __restrict__ hA1, const float* __restrict__ h1v, float* __restrict__ e1)
{
  int b = blockIdx.z;
  int N, i0, j0; const float *Ap, *Hp; float* ep;
  if (blockIdx.y < 16) {
    N = N2S; i0 = blockIdx.y*32; j0 = blockIdx.x*32;
    Ap = hA2 + (size_t)b*N*DD; Hp = h2v + (size_t)b*N*DD; ep = e2 + (size_t)b*N*N;
  } else {
    if (blockIdx.x >= 2) return;
    N = N1S; i0 = (blockIdx.y-16)*32; j0 = blockIdx.x*32;
    Ap = hA1 + (size_t)b*N*DD; Hp = h1v + (size_t)b*N*DD; ep = e1 + (size_t)b*N*N;
  }
  __shared__ float As1[32][36], Hs1[32][36], As2T[32][36], Hs2T[32][36];
  int t = threadIdx.x;
  int lr = t >> 3, lc = t & 7;
  int ti = t >> 3, tj4 = t & 7;
  float acc[4] = {0.f,0.f,0.f,0.f};
  for (int kc = 0; kc < DD; kc += 32) {
    float4 a1 = *(const float4*)(Ap + (size_t)(i0+lr)*DD + kc + lc*4);
    float4 hi = *(const float4*)(Hp + (size_t)(i0+lr)*DD + kc + lc*4);
    float4 a2 = *(const float4*)(Ap + (size_t)(j0+lr)*DD + kc + lc*4);
    float4 hj = *(const float4*)(Hp + (size_t)(j0+lr)*DD + kc + lc*4);
    *(float4*)&As1[lr][lc*4] = a1;
    *(float4*)&Hs1[lr][lc*4] = hi;
    As2T[lc*4+0][lr] = a2.x; As2T[lc*4+1][lr] = a2.y; As2T[lc*4+2][lr] = a2.z; As2T[lc*4+3][lr] = a2.w;
    Hs2T[lc*4+0][lr] = hj.x; Hs2T[lc*4+1][lr] = hj.y; Hs2T[lc*4+2][lr] = hj.z; Hs2T[lc*4+3][lr] = hj.w;
    __syncthreads();
    for (int kk = 0; kk < 32; ++kk) {
      float a  = As1[ti][kk];
      float hv = Hs1[ti][kk];
      float4 h4 = *(const float4*)&Hs2T[kk][tj4*4];
      float4 a4 = *(const float4*)&As2T[kk][tj4*4];
      acc[0] += a*h4.x + hv*a4.x;
      acc[1] += a*h4.y + hv*a4.y;
      acc[2] += a*h4.z + hv*a4.z;
      acc[3] += a*h4.w + hv*a4.w;
    }
    __syncthreads();
  }
  *(float4*)(ep + (size_t)(i0+ti)*N + j0 + tj4*4) = make_float4(acc[0],acc[1],acc[2],acc[3]);
}

// ---- column softmax stats over axis i (both sets): m_j, s_j of masked esym ----
__global__ __launch_bounds__(256) void k_stats(
    const float* __restrict__ e2, const float* __restrict__ adj2,
    float* __restrict__ m2, float* __restrict__ s2v,
    const float* __restrict__ e1, const float* __restrict__ adj1,
    float* __restrict__ m1, float* __restrict__ s1v)
{
  int b = blockIdx.y;
  int tj = threadIdx.x & 63, ti = threadIdx.x >> 6;
  int N, j; const float *ep, *ap; float *ms, *ss;
  if (blockIdx.x < 8) {
    N = N2S; j = blockIdx.x*64 + tj;
    ep = e2 + (size_t)b*N*N; ap = adj2 + (size_t)b*N*N;
    ms = m2 + (size_t)b*N;   ss = s2v + (size_t)b*N;
  } else {
    N = N1S; j = tj;
    ep = e1 + (size_t)b*N*N; ap = adj1 + (size_t)b*N*N;
    ms = m1 + (size_t)b*N;   ss = s1v + (size_t)b*N;
  }
  float m = -3.0e38f, s = 0.f;
  for (int i = ti; i < N; i += 4) {
    float av = ap[(size_t)i*N + j];
    float v = (av > 0.f) ? ep[(size_t)i*N + j] : -9e15f;
    float nm = fmaxf(m, v);
    s = s*__expf(m - nm) + __expf(v - nm);
    m = nm;
  }
  __shared__ float lm[4][64], ls[4][64];
  lm[ti][tj] = m; ls[ti][tj] = s;
  __syncthreads();
  if (ti == 0) {
    float M = lm[0][tj];
    for (int c = 1; c < 4; ++c) M = fmaxf(M, lm[c][tj]);
    float S = 0.f;
    for (int c = 0; c < 4; ++c) S += ls[c][tj]*__expf(lm[c][tj] - M);
    ms[j] = M;
    ss[j] = S;
  }
}

// ---- hp + gate + blend, both sets: grid (144, NB), 128 thr, 4 rows/block ----
__global__ __launch_bounds__(128) void k_hp(
    const float* __restrict__ e2, const float* __restrict__ adj2,
    const float* __restrict__ m2, const float* __restrict__ s2v,
    const float* __restrict__ hb2, const float* __restrict__ x2, float* __restrict__ o2,
    const float* __restrict__ e1, const float* __restrict__ adj1,
    const float* __restrict__ m1, const float* __restrict__ s1v,
    const float* __restrict__ hb1, const float* __restrict__ x1, float* __restrict__ o1,
    const float* __restrict__ Wg, const float* __restrict__ bg)
{
  int b = blockIdx.y; int d = threadIdx.x;
  int N, i0; const float *ep, *ap, *msb, *ssb, *hb, *x; float* out;
  if (blockIdx.x < 128) {
    N = N2S; i0 = blockIdx.x*4;
    ep = e2 + (size_t)b*N*N; ap = adj2 + (size_t)b*N*N;
    msb = m2 + (size_t)b*N;  ssb = s2v + (size_t)b*N;
    hb = hb2 + (size_t)b*N*DD; x = x2 + (size_t)b*N*DD; out = o2 + (size_t)b*N*DD;
  } else {
    N = N1S; i0 = (blockIdx.x-128)*4;
    ep = e1 + (size_t)b*N*N; ap = adj1 + (size_t)b*N*N;
    msb = m1 + (size_t)b*N;  ssb = s1v + (size_t)b*N;
    hb = hb1 + (size_t)b*N*DD; x = x1 + (size_t)b*N*DD; out = o1 + (size_t)b*N*DD;
  }
  __shared__ float ps[4][DD];
  __shared__ float wred[4][2];
  float hp[4] = {0.f,0.f,0.f,0.f};
  for (int j0 = 0; j0 < N; j0 += DD) {
    int j = j0 + d;
    if (j < N) {
      float mj = msb[j], sj = ssb[j];
      for (int r = 0; r < 4; ++r) {
        int i = i0 + r;
        float av = ap[(size_t)i*N + j];
        float p = 0.f;
        if (av > 0.f)
          p = __expf(ep[(size_t)i*N + j] - mj) / sj;
        ps[r][d] = p;
      }
    } else {
      for (int r = 0; r < 4; ++r) ps[r][d] = 0.f;
    }
    __syncthreads();
    int jmax = min(DD, N - j0);
    for (int jj = 0; jj < jmax; ++jj) {
      float hv = hb[(size_t)(j0+jj)*DD + d];
      hp[0] += ps[0][jj]*hv;
      hp[1] += ps[1][jj]*hv;
      hp[2] += ps[2][jj]*hv;
      hp[3] += ps[3][jj]*hv;
    }
    __syncthreads();
  }
  // gate: per-wave shfl reduce (one sync total for all 4 rows)
  float hpr[4], xv[4];
  for (int r = 0; r < 4; ++r) {
    int i = i0 + r;
    hpr[r] = fmaxf(hp[r], 0.f);
    xv[r] = x[(size_t)i*DD + d];
    float rv = xv[r]*Wg[d] + hpr[r]*Wg[DD + d];
    for (int off = 32; off; off >>= 1) rv += __shfl_xor(rv, off);
    if ((d & 63) == 0) wred[r][d >> 6] = rv;
  }
  __syncthreads();
  float bg0 = bg[0];
  for (int r = 0; r < 4; ++r) {
    int i = i0 + r;
    float coeff = 1.f/(1.f + __expf(-(wred[r][0] + wred[r][1] + bg0)));
    out[(size_t)i*DD + d] = coeff*xv[r] + (1.f - coeff)*hpr[r];
  }
}

// ------- build active (i1,i2) lists; LDS-aggregated -> ONE atomic per block -------
// 32768 pairs per (b,t); 256 | 32768 so each block lies in a single bt.
__global__ __launch_bounds__(256) void k_build(const float* __restrict__ A_int,
                                               int* __restrict__ counts,
                                               int* __restrict__ lists) {
  int idx = blockIdx.x*256 + threadIdx.x;
  bool active = (A_int[idx] != 0.f);
  unsigned long long mask = __ballot(active);
  int lane = threadIdx.x & 63;
  int w = threadIdx.x >> 6;
  int bt = idx >> 15;
  int before = __popcll(mask & ((1ull << lane) - 1ull));
  int n = __popcll(mask);
  __shared__ int wcnt[4];
  __shared__ int blockBase;
  if (lane == 0) wcnt[w] = n;
  __syncthreads();
  if (threadIdx.x == 0) {
    int total = wcnt[0] + wcnt[1] + wcnt[2] + wcnt[3];
    blockBase = total ? atomicAdd(&counts[bt*CSTR], total) : 0;
    int run = 0;
    for (int i = 0; i < 4; ++i) { int c = wcnt[i]; wcnt[i] = run; run += c; }
  }
  __syncthreads();
  if (active) {
    int pos = blockBase + wcnt[w] + before;
    if (pos < LCAP) lists[bt*LCAP + pos] = idx & 32767;  // (i1<<9)|i2
  }
}

// ------- sparse pair phase: hid = relu(U1[i1]+U2[i2]); sig(hid.W2+b2) -------
__global__ __launch_bounds__(256) void k_pair(
    const float* __restrict__ U1A, const float* __restrict__ U2A,
    const float* __restrict__ U1B, const float* __restrict__ U2B,
    const float* __restrict__ WA2, const float* __restrict__ bA2,
    const float* __restrict__ WB2, const float* __restrict__ bB2,
    const float* __restrict__ dmv, const float* __restrict__ Cv,
    const int* __restrict__ lists, const int* __restrict__ counts,
    float* __restrict__ retval)
{
  int bt = blockIdx.y; int b = bt / NT, t = bt % NT;
  int cnt = min(counts[bt*CSTR], LCAP);
  __shared__ __align__(16) float w2a[HH], w2b[HH];
  int tid = threadIdx.x;
  if (tid < HH) w2a[tid] = WA2[t*HH + tid];
  else          w2b[tid-HH] = WB2[t*HH + tid - HH];
  __syncthreads();
  int lane = tid & 63, w = tid >> 6;
  float bcv = BCON[t];
  float bcinv = 1.f/(3.f*bcv*bcv);
  float b2a = bA2[t], b2b = bB2[t], c = Cv[t];
  const float* u1a = U1A + (size_t)t*NB*N1S*DD + (size_t)b*N1S*DD;
  const float* u2a = U2A + (size_t)t*NB*N2S*DD + (size_t)b*N2S*DD;
  const float* u1b = U1B + (size_t)t*NB*N1S*DD + (size_t)b*N1S*DD;
  const float* u2b = U2B + (size_t)t*NB*N2S*DD + (size_t)b*N2S*DD;
  float2 wva = ((const float2*)w2a)[lane];
  float2 wvb = ((const float2*)w2b)[lane];
  float acc = 0.f;
  for (int p = blockIdx.x*4 + w; p < cnt; p += gridDim.x*4) {
    int id = lists[bt*LCAP + p];
    int i1 = id >> 9, i2 = id & 511;
    float2 a1 = ((const float2*)(u1a + (size_t)i1*DD))[lane];
    float2 a2 = ((const float2*)(u2a + (size_t)i2*DD))[lane];
    float2 b1 = ((const float2*)(u1b + (size_t)i1*DD))[lane];
    float2 b2 = ((const float2*)(u2b + (size_t)i2*DD))[lane];
    float pA = fmaxf(a1.x + a2.x, 0.f)*wva.x + fmaxf(a1.y + a2.y, 0.f)*wva.y;
    float pB = fmaxf(b1.x + b2.x, 0.f)*wvb.x + fmaxf(b1.y + b2.y, 0.f)*wvb.y;
    for (int off = 32; off; off >>= 1) {
      pA += __shfl_xor(pA, off);
      pB += __shfl_xor(pB, off);
    }
    float Aval = 4.f/(1.f + __expf(-(pA + b2a)));
    float Bval = (2.f*bcinv)/(1.f + __expf(-(pB + b2b))) + bcinv;
    const float* dp = dmv + (((size_t)b*N1S + i1)*N2S + i2)*3;
    float dx = dp[0], dy = dp[1], dz = dp[2];
    float dm = sqrtf(dx*dx + dy*dy + dz*dz + 1e-10f);
    if (dm < 0.5f) dm = 1e10f;
    float diff = dm - c;
    float ev = Aval*(Bval*diff*diff - 1.f);
    if (lane == 0) acc += ev;
  }
  __shared__ float wsum[4];
  if (lane == 0) wsum[w] = acc;
  __syncthreads();
  if (tid == 0)
    atomicAdd(&retval[bt], wsum[0]+wsum[1]+wsum[2]+wsum[3]);
}

// ---------------- pooled intercept + final output ----------------
__global__ __launch_bounds__(128) void k_intercept(const float* __restrict__ h1e,
                                                   const float* __restrict__ valid,
                                                   const float* __restrict__ Wi1,
                                                   const float* __restrict__ bi1,
                                                   const float* __restrict__ Wi2,
                                                   const float* __restrict__ bi2,
                                                   const float* __restrict__ retval,
                                                   float* __restrict__ out) {
  int b = blockIdx.x; int d = threadIdx.x;
  __shared__ float pooled[DD], hid[DD], red[DD];
  float s = 0.f;
  for (int i = 0; i < N1S; ++i)
    s += h1e[((size_t)b*N1S + i)*DD + d] * valid[b*N1S + i];
  pooled[d] = s;
  __syncthreads();
  float a = bi1[d];
  for (int k = 0; k < DD; ++k) a += pooled[k]*Wi1[k*HH + d];
  hid[d] = fmaxf(a, 0.f);
  __syncthreads();
  red[d] = hid[d]*Wi2[d];
  __syncthreads();
  for (int s2 = 64; s2 > 0; s2 >>= 1) {
    if (d < s2) red[d] += red[d + s2];
    __syncthreads();
  }
  float inter = 4.f/(1.f + __expf(-(red[0] + bi2[0])));
  if (d < NT) out[b*NT + d] = retval[b*NT + d] + inter/(float)NT;
}

extern "C" void kernel_launch(void* const* d_in, const int* in_sizes, int n_in,
                              void* d_out, int out_size, void* d_ws, size_t ws_size,
                              hipStream_t stream) {
  (void)in_sizes; (void)n_in; (void)out_size; (void)ws_size;
  const float* h1     = (const float*)d_in[0];
  const float* adj1   = (const float*)d_in[1];
  const float* h2     = (const float*)d_in[2];
  const float* adj2   = (const float*)d_in[3];
  const float* A_int  = (const float*)d_in[4];
  const float* dmv    = (const float*)d_in[5];
  const float* valid  = (const float*)d_in[6];
  const float* W_embed= (const float*)d_in[7];
  const float* gW     = (const float*)d_in[8];
  const float* gWb    = (const float*)d_in[9];
  const float* gA     = (const float*)d_in[10];
  const float* gGateW = (const float*)d_in[11];
  const float* gGateb = (const float*)d_in[12];
  const float* WA1    = (const float*)d_in[13];
  const float* bA1    = (const float*)d_in[14];
  const float* WA2    = (const float*)d_in[15];
  const float* bA2    = (const float*)d_in[16];
  const float* WB1    = (const float*)d_in[17];
  const float* bB1    = (const float*)d_in[18];
  const float* WB2    = (const float*)d_in[19];
  const float* bB2    = (const float*)d_in[20];
  const float* Cv     = (const float*)d_in[21];
  const float* Wi1    = (const float*)d_in[22];
  const float* bi1    = (const float*)d_in[23];
  const float* Wi2    = (const float*)d_in[24];
  const float* bi2    = (const float*)d_in[25];

  float* base = (float*)d_ws;
  size_t off = 0;
  auto alloc = [&](size_t n) { float* p = base + off; off += n; return p; };
  float* h1a   = alloc((size_t)NB*N1S*DD);
  float* h1b   = alloc((size_t)NB*N1S*DD);
  float* h2a   = alloc((size_t)NB*N2S*DD);
  float* h2b   = alloc((size_t)NB*N2S*DD);
  float* hb1   = alloc((size_t)NB*N1S*DD);
  float* hAb1  = alloc((size_t)NB*N1S*DD);
  float* hb2   = alloc((size_t)NB*N2S*DD);
  float* hAb2  = alloc((size_t)NB*N2S*DD);
  float* e1    = alloc((size_t)NB*N1S*N1S);
  float* e2    = alloc((size_t)NB*N2S*N2S);
  float* m1    = alloc((size_t)NB*N1S);
  float* s1    = alloc((size_t)NB*N1S);
  float* m2    = alloc((size_t)NB*N2S);
  float* s2    = alloc((size_t)NB*N2S);
  float* U1A   = alloc((size_t)NT*NB*N1S*DD);
  float* U2A   = alloc((size_t)NT*NB*N2S*DD);
  float* U1B   = alloc((size_t)NT*NB*N1S*DD);
  float* U2B   = alloc((size_t)NT*NB*N2S*DD);
  float* retval= alloc(NB*NT);
  int*   counts= (int*)alloc(NB*NT*CSTR);
  int*   lists = (int*)alloc((size_t)NB*NT*LCAP);

  hipMemsetAsync(retval, 0, NB*NT*sizeof(float), stream);
  hipMemsetAsync(counts, 0, NB*NT*CSTR*sizeof(int), stream);

  // sparse list build (independent of GAT chain)
  k_build<<<dim3((NB*NT*N1S*N2S)/256), 256, 0, stream>>>(A_int, counts, lists);

  k_embed<<<dim3(NB*(N1S+N2S)), 128, 0, stream>>>(h1, h2, W_embed, h1a, h2a);

  float* c1 = h1a; float* o1 = h1b;
  float* c2 = h2a; float* o2 = h2b;
  for (int l = 0; l < 3; ++l) {
    const float* W  = gW + (size_t)l*DD*DD;
    const float* Wb = gWb + (size_t)l*DD;
    const float* A  = gA + (size_t)l*DD*DD;
    const float* Wg = gGateW + (size_t)l*2*DD;
    const float* bg = gGateb + l;
    k_gemm128<<<dim3(4, 144), 256, 0, stream>>>(c1, c2, 16, W, Wb, hb1, hb2);
    k_gemm128<<<dim3(4, 144), 256, 0, stream>>>(hb1, hb2, 16, A, nullptr, hAb1, hAb2);
    k_egemm<<<dim3(16, 18, NB), 256, 0, stream>>>(hAb2, hb2, e2, hAb1, hb1, e1);
    k_stats<<<dim3(9, NB), 256, 0, stream>>>(e2, adj2, m2, s2, e1, adj1, m1, s1);
    k_hp<<<dim3(144, NB), 128, 0, stream>>>(e2, adj2, m2, s2, hb2, c2, o2,
                                            e1, adj1, m1, s1, hb1, c1, o1, Wg, bg);
    float* tmp;
    tmp = c1; c1 = o1; o1 = tmp;
    tmp = c2; c2 = o2; o2 = tmp;
  }

  // U1 = h1e @ W1_top (+b1); U2 = h2e @ W1_bot  — all 14 (t,mlp) in one launch
  k_ugemm<<<dim3(4, 144, 14), 256, 0, stream>>>(c1, c2, WA1, bA1, WB1, bB1,
                                                U1A, U2A, U1B, U2B);
  k_pair<<<dim3(32, NB*NT), 256, 0, stream>>>(U1A, U2A, U1B, U2B,
      WA2, bA2, WB2, bB2, dmv, Cv, lists, counts, retval);

  k_intercept<<<dim3(NB), 128, 0, stream>>>(c1, valid, Wi1, bi1, Wi2, bi2, retval,
                                            (float*)d_out);
}

// Round 10
// 488.797 us; speedup vs baseline: 1.8273x; 1.4102x over previous
//
#include <hip/hip_runtime.h>
#include <hip/hip_bf16.h>

// Problem constants
#define NB 8
#define N1S 64
#define N2S 512
#define DD 128
#define HH 128
#define NT 7
#define LCAP 4096   // per-(b,t) list capacity
#define CSTR 16     // counts[] stride in ints (64B line) to kill atomic contention
#define SCH 16      // row-chunks for set2 stats partial reduction

__device__ __constant__ float BCON[NT] = {1.159f,0.448f,0.927f,0.902f,0.349f,0.789f,0.198f};

// ---------------- embed: out[row,:] = x[row,:56] @ W[56,128] ----------------
__global__ __launch_bounds__(128) void k_embed(const float* __restrict__ x1,
                                               const float* __restrict__ x2,
                                               const float* __restrict__ W,
                                               float* __restrict__ o1,
                                               float* __restrict__ o2) {
  int row = blockIdx.x; int d = threadIdx.x;
  const float* x; float* out;
  if (row < NB*N1S) { x = x1 + (size_t)row*56;            out = o1 + (size_t)row*DD; }
  else              { x = x2 + (size_t)(row-NB*N1S)*56;   out = o2 + (size_t)(row-NB*N1S)*DD; }
  __shared__ float xs[64];
  if (d < 56) xs[d] = x[d];
  __syncthreads();
  float acc = 0.f;
  for (int k = 0; k < 56; ++k) acc += xs[k] * W[k*DD + d];
  out[d] = acc;
}

// ---- tiled GEMM  C = A @ B (+bias), K=128, two row-sources in one launch ----
__global__ __launch_bounds__(256) void k_gemm128(
    const float* __restrict__ A1, const float* __restrict__ A2, int split,
    const float* __restrict__ Bw, const float* __restrict__ bias,
    float* __restrict__ C1, float* __restrict__ C2)
{
  int yb = blockIdx.y;
  const float* A; float* C; int row0;
  if (yb < split) { A = A1; C = C1; row0 = yb*32; }
  else            { A = A2; C = C2; row0 = (yb-split)*32; }
  int j0 = blockIdx.x*32;
  __shared__ float As[32][36], Bs[32][36];   // pad 36 keeps float4 LDS ops 16B-aligned
  int t = threadIdx.x;
  int lr = t >> 3, lc = t & 7;
  int ti = t >> 3, tj4 = t & 7;
  float acc[4] = {0.f,0.f,0.f,0.f};
  for (int kc = 0; kc < 128; kc += 32) {
    float4 av = *(const float4*)(A  + (size_t)(row0+lr)*128 + kc + lc*4);
    float4 bv = *(const float4*)(Bw + (size_t)(kc+lr)*128 + j0 + lc*4);
    *(float4*)&As[lr][lc*4] = av;
    *(float4*)&Bs[lr][lc*4] = bv;
    __syncthreads();
    for (int kk = 0; kk < 32; ++kk) {
      float a = As[ti][kk];
      float4 b4 = *(const float4*)&Bs[kk][tj4*4];
      acc[0] += a*b4.x; acc[1] += a*b4.y; acc[2] += a*b4.z; acc[3] += a*b4.w;
    }
    __syncthreads();
  }
  if (bias) {
    const float* bp = bias + j0 + tj4*4;
    acc[0] += bp[0]; acc[1] += bp[1]; acc[2] += bp[2]; acc[3] += bp[3];
  }
  *(float4*)(C + (size_t)(row0+ti)*128 + j0 + tj4*4) = make_float4(acc[0],acc[1],acc[2],acc[3]);
}

// ---- U-precompute: all 14 (type,mlp) first-layer GEMMs in one launch ----
__global__ __launch_bounds__(256) void k_ugemm(
    const float* __restrict__ c1, const float* __restrict__ c2,
    const float* __restrict__ WA1, const float* __restrict__ bA1,
    const float* __restrict__ WB1, const float* __restrict__ bB1,
    float* __restrict__ U1A, float* __restrict__ U2A,
    float* __restrict__ U1B, float* __restrict__ U2B)
{
  int z = blockIdx.z;
  int t7 = (z < 7) ? z : z - 7;
  const float* W1 = (z < 7 ? WA1 : WB1) + (size_t)t7*2*DD*HH;
  int yb = blockIdx.y;
  const float* A; float* C; int row0; const float* bias;
  if (yb < 16) {
    A = c1; row0 = yb*32;
    C = (z < 7 ? U1A : U1B) + (size_t)t7*NB*N1S*DD;
    bias = (z < 7 ? bA1 : bB1) + t7*HH;
  } else {
    A = c2; row0 = (yb-16)*32;
    C = (z < 7 ? U2A : U2B) + (size_t)t7*NB*N2S*DD;
    W1 += DD*HH;
    bias = nullptr;
  }
  int j0 = blockIdx.x*32;
  __shared__ float As[32][36], Bs[32][36];
  int t = threadIdx.x;
  int lr = t >> 3, lc = t & 7;
  int ti = t >> 3, tj4 = t & 7;
  float acc[4] = {0.f,0.f,0.f,0.f};
  for (int kc = 0; kc < 128; kc += 32) {
    float4 av = *(const float4*)(A  + (size_t)(row0+lr)*128 + kc + lc*4);
    float4 bv = *(const float4*)(W1 + (size_t)(kc+lr)*128 + j0 + lc*4);
    *(float4*)&As[lr][lc*4] = av;
    *(float4*)&Bs[lr][lc*4] = bv;
    __syncthreads();
    for (int kk = 0; kk < 32; ++kk) {
      float a = As[ti][kk];
      float4 b4 = *(const float4*)&Bs[kk][tj4*4];
      acc[0] += a*b4.x; acc[1] += a*b4.y; acc[2] += a*b4.z; acc[3] += a*b4.w;
    }
    __syncthreads();
  }
  if (bias) {
    const float* bp = bias + j0 + tj4*4;
    acc[0] += bp[0]; acc[1] += bp[1]; acc[2] += bp[2]; acc[3] += bp[3];
  }
  *(float4*)(C + (size_t)(row0+ti)*128 + j0 + tj4*4) = make_float4(acc[0],acc[1],acc[2],acc[3]);
}

// ---- esym[b,i,j] = hA[i].h[j] + h[i].hA[j]  (symmetric; both sets) ----
__global__ __launch_bounds__(256) void k_egemm(
    const float* __restrict__ hA2, const float* __restrict__ h2v, float* __restrict__ e2,
    const float* __restrict__ hA1, const float* __restrict__ h1v, float* __restrict__ e1)
{
  int b = blockIdx.z;
  int N, i0, j0; const float *Ap, *Hp; float* ep;
  if (blockIdx.y < 16) {
    N = N2S; i0 = blockIdx.y*32; j0 = blockIdx.x*32;
    Ap = hA2 + (size_t)b*N*DD; Hp = h2v + (size_t)b*N*DD; ep = e2 + (size_t)b*N*N;
  } else {
    if (blockIdx.x >= 2) return;
    N = N1S; i0 = (blockIdx.y-16)*32; j0 = blockIdx.x*32;
    Ap = hA1 + (size_t)b*N*DD; Hp = h1v + (size_t)b*N*DD; ep = e1 + (size_t)b*N*N;
  }
  __shared__ float As1[32][36], Hs1[32][36], As2T[32][36], Hs2T[32][36];
  int t = threadIdx.x;
  int lr = t >> 3, lc = t & 7;
  int ti = t >> 3, tj4 = t & 7;
  float acc[4] = {0.f,0.f,0.f,0.f};
  for (int kc = 0; kc < DD; kc += 32) {
    float4 a1 = *(const float4*)(Ap + (size_t)(i0+lr)*DD + kc + lc*4);
    float4 hi = *(const float4*)(Hp + (size_t)(i0+lr)*DD + kc + lc*4);
    float4 a2 = *(const float4*)(Ap + (size_t)(j0+lr)*DD + kc + lc*4);
    float4 hj = *(const float4*)(Hp + (size_t)(j0+lr)*DD + kc + lc*4);
    *(float4*)&As1[lr][lc*4] = a1;
    *(float4*)&Hs1[lr][lc*4] = hi;
    As2T[lc*4+0][lr] = a2.x; As2T[lc*4+1][lr] = a2.y; As2T[lc*4+2][lr] = a2.z; As2T[lc*4+3][lr] = a2.w;
    Hs2T[lc*4+0][lr] = hj.x; Hs2T[lc*4+1][lr] = hj.y; Hs2T[lc*4+2][lr] = hj.z; Hs2T[lc*4+3][lr] = hj.w;
    __syncthreads();
    for (int kk = 0; kk < 32; ++kk) {
      float a  = As1[ti][kk];
      float hv = Hs1[ti][kk];
      float4 h4 = *(const float4*)&Hs2T[kk][tj4*4];
      float4 a4 = *(const float4*)&As2T[kk][tj4*4];
      acc[0] += a*h4.x + hv*a4.x;
      acc[1] += a*h4.y + hv*a4.y;
      acc[2] += a*h4.z + hv*a4.z;
      acc[3] += a*h4.w + hv*a4.w;
    }
    __syncthreads();
  }
  *(float4*)(ep + (size_t)(i0+ti)*N + j0 + tj4*4) = make_float4(acc[0],acc[1],acc[2],acc[3]);
}

// ---- stats phase 1: per-row-chunk partial (m,s) of masked esym columns ----
// grid (9, SCH, NB): x<8 -> set2 col-block (64 cols) x row-chunk y (32 rows);
// x==8,y==0 -> set1 (64 cols, all 64 rows, direct write).
__global__ __launch_bounds__(256) void k_stats(
    const float* __restrict__ e2, const float* __restrict__ adj2,
    float* __restrict__ pm2, float* __restrict__ ps2,
    const float* __restrict__ e1, const float* __restrict__ adj1,
    float* __restrict__ m1, float* __restrict__ s1v)
{
  int b = blockIdx.z;
  int tj = threadIdx.x & 63, ti = threadIdx.x >> 6;
  __shared__ float lm[4][64], ls[4][64];
  if (blockIdx.x < 8) {
    const int N = N2S;
    int j = blockIdx.x*64 + tj;
    const float* ep = e2 + (size_t)b*N*N;
    const float* ap = adj2 + (size_t)b*N*N;
    int ibase = blockIdx.y*32 + ti;
    float v[8];
    #pragma unroll
    for (int r = 0; r < 8; ++r) {
      int i = ibase + r*4;
      float av = ap[(size_t)i*N + j];
      float evv = ep[(size_t)i*N + j];
      v[r] = (av > 0.f) ? evv : -9e15f;
    }
    float m = v[0];
    #pragma unroll
    for (int r = 1; r < 8; ++r) m = fmaxf(m, v[r]);
    float s = 0.f;
    #pragma unroll
    for (int r = 0; r < 8; ++r) s += __expf(v[r] - m);
    lm[ti][tj] = m; ls[ti][tj] = s;
    __syncthreads();
    if (ti == 0) {
      float M = fmaxf(fmaxf(lm[0][tj], lm[1][tj]), fmaxf(lm[2][tj], lm[3][tj]));
      float S = ls[0][tj]*__expf(lm[0][tj]-M) + ls[1][tj]*__expf(lm[1][tj]-M)
              + ls[2][tj]*__expf(lm[2][tj]-M) + ls[3][tj]*__expf(lm[3][tj]-M);
      size_t o = ((size_t)blockIdx.y*NB + b)*N2S + j;
      pm2[o] = M; ps2[o] = S;
    }
  } else {
    if (blockIdx.y != 0) return;
    const int N = N1S;
    int j = tj;
    const float* ep = e1 + (size_t)b*N*N;
    const float* ap = adj1 + (size_t)b*N*N;
    float v[16];
    #pragma unroll
    for (int r = 0; r < 16; ++r) {
      int i = ti + r*4;
      float av = ap[(size_t)i*N + j];
      float evv = ep[(size_t)i*N + j];
      v[r] = (av > 0.f) ? evv : -9e15f;
    }
    float m = v[0];
    #pragma unroll
    for (int r = 1; r < 16; ++r) m = fmaxf(m, v[r]);
    float s = 0.f;
    #pragma unroll
    for (int r = 0; r < 16; ++r) s += __expf(v[r] - m);
    lm[ti][tj] = m; ls[ti][tj] = s;
    __syncthreads();
    if (ti == 0) {
      float M = fmaxf(fmaxf(lm[0][tj], lm[1][tj]), fmaxf(lm[2][tj], lm[3][tj]));
      float S = ls[0][tj]*__expf(lm[0][tj]-M) + ls[1][tj]*__expf(lm[1][tj]-M)
              + ls[2][tj]*__expf(lm[2][tj]-M) + ls[3][tj]*__expf(lm[3][tj]-M);
      m1[(size_t)b*N + j] = M;
      s1v[(size_t)b*N + j] = S;
    }
  }
}

// ---- stats phase 2: combine SCH partials per set2 column ----
__global__ __launch_bounds__(512) void k_scomb(const float* __restrict__ pm2,
                                               const float* __restrict__ ps2,
                                               float* __restrict__ m2,
                                               float* __restrict__ s2v) {
  int b = blockIdx.x; int j = threadIdx.x;  // 512 columns
  float m = -3.0e38f;
  #pragma unroll
  for (int c = 0; c < SCH; ++c) m = fmaxf(m, pm2[((size_t)c*NB + b)*N2S + j]);
  float s = 0.f;
  #pragma unroll
  for (int c = 0; c < SCH; ++c) {
    size_t o = ((size_t)c*NB + b)*N2S + j;
    s += ps2[o]*__expf(pm2[o] - m);
  }
  m2[(size_t)b*N2S + j] = m;
  s2v[(size_t)b*N2S + j] = s;
}

// ---- hp + gate + blend, both sets: grid (144, NB), 128 thr, 4 rows/block ----
__global__ __launch_bounds__(128) void k_hp(
    const float* __restrict__ e2, const float* __restrict__ adj2,
    const float* __restrict__ m2, const float* __restrict__ s2v,
    const float* __restrict__ hb2, const float* __restrict__ x2, float* __restrict__ o2,
    const float* __restrict__ e1, const float* __restrict__ adj1,
    const float* __restrict__ m1, const float* __restrict__ s1v,
    const float* __restrict__ hb1, const float* __restrict__ x1, float* __restrict__ o1,
    const float* __restrict__ Wg, const float* __restrict__ bg)
{
  int b = blockIdx.y; int d = threadIdx.x;
  int N, i0; const float *ep, *ap, *msb, *ssb, *hb, *x; float* out;
  if (blockIdx.x < 128) {
    N = N2S; i0 = blockIdx.x*4;
    ep = e2 + (size_t)b*N*N; ap = adj2 + (size_t)b*N*N;
    msb = m2 + (size_t)b*N;  ssb = s2v + (size_t)b*N;
    hb = hb2 + (size_t)b*N*DD; x = x2 + (size_t)b*N*DD; out = o2 + (size_t)b*N*DD;
  } else {
    N = N1S; i0 = (blockIdx.x-128)*4;
    ep = e1 + (size_t)b*N*N; ap = adj1 + (size_t)b*N*N;
    msb = m1 + (size_t)b*N;  ssb = s1v + (size_t)b*N;
    hb = hb1 + (size_t)b*N*DD; x = x1 + (size_t)b*N*DD; out = o1 + (size_t)b*N*DD;
  }
  __shared__ float ps[4][DD];
  __shared__ float wred[4][2];
  float hp[4] = {0.f,0.f,0.f,0.f};
  for (int j0 = 0; j0 < N; j0 += DD) {
    int j = j0 + d;
    if (j < N) {
      float mj = msb[j], sj = ssb[j];
      for (int r = 0; r < 4; ++r) {
        int i = i0 + r;
        float av = ap[(size_t)i*N + j];
        float p = 0.f;
        if (av > 0.f)
          p = __expf(ep[(size_t)i*N + j] - mj) / sj;
        ps[r][d] = p;
      }
    } else {
      for (int r = 0; r < 4; ++r) ps[r][d] = 0.f;
    }
    __syncthreads();
    int jmax = min(DD, N - j0);
    for (int jj = 0; jj < jmax; ++jj) {
      float hv = hb[(size_t)(j0+jj)*DD + d];
      hp[0] += ps[0][jj]*hv;
      hp[1] += ps[1][jj]*hv;
      hp[2] += ps[2][jj]*hv;
      hp[3] += ps[3][jj]*hv;
    }
    __syncthreads();
  }
  // gate: per-wave shfl reduce (one sync total for all 4 rows)
  float hpr[4], xv[4];
  for (int r = 0; r < 4; ++r) {
    int i = i0 + r;
    hpr[r] = fmaxf(hp[r], 0.f);
    xv[r] = x[(size_t)i*DD + d];
    float rv = xv[r]*Wg[d] + hpr[r]*Wg[DD + d];
    for (int off = 32; off; off >>= 1) rv += __shfl_xor(rv, off);
    if ((d & 63) == 0) wred[r][d >> 6] = rv;
  }
  __syncthreads();
  float bg0 = bg[0];
  for (int r = 0; r < 4; ++r) {
    int i = i0 + r;
    float coeff = 1.f/(1.f + __expf(-(wred[r][0] + wred[r][1] + bg0)));
    out[(size_t)i*DD + d] = coeff*xv[r] + (1.f - coeff)*hpr[r];
  }
}

// ------- build active (i1,i2) lists; LDS-aggregated -> ONE atomic per block -------
__global__ __launch_bounds__(256) void k_build(const float* __restrict__ A_int,
                                               int* __restrict__ counts,
                                               int* __restrict__ lists) {
  int idx = blockIdx.x*256 + threadIdx.x;
  bool active = (A_int[idx] != 0.f);
  unsigned long long mask = __ballot(active);
  int lane = threadIdx.x & 63;
  int w = threadIdx.x >> 6;
  int bt = idx >> 15;
  int before = __popcll(mask & ((1ull << lane) - 1ull));
  int n = __popcll(mask);
  __shared__ int wcnt[4];
  __shared__ int blockBase;
  if (lane == 0) wcnt[w] = n;
  __syncthreads();
  if (threadIdx.x == 0) {
    int total = wcnt[0] + wcnt[1] + wcnt[2] + wcnt[3];
    blockBase = total ? atomicAdd(&counts[bt*CSTR], total) : 0;
    int run = 0;
    for (int i = 0; i < 4; ++i) { int c = wcnt[i]; wcnt[i] = run; run += c; }
  }
  __syncthreads();
  if (active) {
    int pos = blockBase + wcnt[w] + before;
    if (pos < LCAP) lists[bt*LCAP + pos] = idx & 32767;  // (i1<<9)|i2
  }
}

// ------- sparse pair phase: hid = relu(U1[i1]+U2[i2]); sig(hid.W2+b2) -------
__global__ __launch_bounds__(256) void k_pair(
    const float* __restrict__ U1A, const float* __restrict__ U2A,
    const float* __restrict__ U1B, const float* __restrict__ U2B,
    const float* __restrict__ WA2, const float* __restrict__ bA2,
    const float* __restrict__ WB2, const float* __restrict__ bB2,
    const float* __restrict__ dmv, const float* __restrict__ Cv,
    const int* __restrict__ lists, const int* __restrict__ counts,
    float* __restrict__ retval)
{
  int bt = blockIdx.y; int b = bt / NT, t = bt % NT;
  int cnt = min(counts[bt*CSTR], LCAP);
  __shared__ __align__(16) float w2a[HH], w2b[HH];
  int tid = threadIdx.x;
  if (tid < HH) w2a[tid] = WA2[t*HH + tid];
  else          w2b[tid-HH] = WB2[t*HH + tid - HH];
  __syncthreads();
  int lane = tid & 63, w = tid >> 6;
  float bcv = BCON[t];
  float bcinv = 1.f/(3.f*bcv*bcv);
  float b2a = bA2[t], b2b = bB2[t], c = Cv[t];
  const float* u1a = U1A + (size_t)t*NB*N1S*DD + (size_t)b*N1S*DD;
  const float* u2a = U2A + (size_t)t*NB*N2S*DD + (size_t)b*N2S*DD;
  const float* u1b = U1B + (size_t)t*NB*N1S*DD + (size_t)b*N1S*DD;
  const float* u2b = U2B + (size_t)t*NB*N2S*DD + (size_t)b*N2S*DD;
  float2 wva = ((const float2*)w2a)[lane];
  float2 wvb = ((const float2*)w2b)[lane];
  float acc = 0.f;
  for (int p = blockIdx.x*4 + w; p < cnt; p += gridDim.x*4) {
    int id = lists[bt*LCAP + p];
    int i1 = id >> 9, i2 = id & 511;
    float2 a1 = ((const float2*)(u1a + (size_t)i1*DD))[lane];
    float2 a2 = ((const float2*)(u2a + (size_t)i2*DD))[lane];
    float2 b1 = ((const float2*)(u1b + (size_t)i1*DD))[lane];
    float2 b2 = ((const float2*)(u2b + (size_t)i2*DD))[lane];
    float pA = fmaxf(a1.x + a2.x, 0.f)*wva.x + fmaxf(a1.y + a2.y, 0.f)*wva.y;
    float pB = fmaxf(b1.x + b2.x, 0.f)*wvb.x + fmaxf(b1.y + b2.y, 0.f)*wvb.y;
    for (int off = 32; off; off >>= 1) {
      pA += __shfl_xor(pA, off);
      pB += __shfl_xor(pB, off);
    }
    float Aval = 4.f/(1.f + __expf(-(pA + b2a)));
    float Bval = (2.f*bcinv)/(1.f + __expf(-(pB + b2b))) + bcinv;
    const float* dp = dmv + (((size_t)b*N1S + i1)*N2S + i2)*3;
    float dx = dp[0], dy = dp[1], dz = dp[2];
    float dm = sqrtf(dx*dx + dy*dy + dz*dz + 1e-10f);
    if (dm < 0.5f) dm = 1e10f;
    float diff = dm - c;
    float ev = Aval*(Bval*diff*diff - 1.f);
    if (lane == 0) acc += ev;
  }
  __shared__ float wsum[4];
  if (lane == 0) wsum[w] = acc;
  __syncthreads();
  if (tid == 0)
    atomicAdd(&retval[bt], wsum[0]+wsum[1]+wsum[2]+wsum[3]);
}

// ---------------- pooled intercept + final output ----------------
__global__ __launch_bounds__(128) void k_intercept(const float* __restrict__ h1e,
                                                   const float* __restrict__ valid,
                                                   const float* __restrict__ Wi1,
                                                   const float* __restrict__ bi1,
                                                   const float* __restrict__ Wi2,
                                                   const float* __restrict__ bi2,
                                                   const float* __restrict__ retval,
                                                   float* __restrict__ out) {
  int b = blockIdx.x; int d = threadIdx.x;
  __shared__ float pooled[DD], hid[DD], red[DD];
  float s = 0.f;
  for (int i = 0; i < N1S; ++i)
    s += h1e[((size_t)b*N1S + i)*DD + d] * valid[b*N1S + i];
  pooled[d] = s;
  __syncthreads();
  float a = bi1[d];
  for (int k = 0; k < DD; ++k) a += pooled[k]*Wi1[k*HH + d];
  hid[d] = fmaxf(a, 0.f);
  __syncthreads();
  red[d] = hid[d]*Wi2[d];
  __syncthreads();
  for (int s2 = 64; s2 > 0; s2 >>= 1) {
    if (d < s2) red[d] += red[d + s2];
    __syncthreads();
  }
  float inter = 4.f/(1.f + __expf(-(red[0] + bi2[0])));
  if (d < NT) out[b*NT + d] = retval[b*NT + d] + inter/(float)NT;
}

extern "C" void kernel_launch(void* const* d_in, const int* in_sizes, int n_in,
                              void* d_out, int out_size, void* d_ws, size_t ws_size,
                              hipStream_t stream) {
  (void)in_sizes; (void)n_in; (void)out_size; (void)ws_size;
  const float* h1     = (const float*)d_in[0];
  const float* adj1   = (const float*)d_in[1];
  const float* h2     = (const float*)d_in[2];
  const float* adj2   = (const float*)d_in[3];
  const float* A_int  = (const float*)d_in[4];
  const float* dmv    = (const float*)d_in[5];
  const float* valid  = (const float*)d_in[6];
  const float* W_embed= (const float*)d_in[7];
  const float* gW     = (const float*)d_in[8];
  const float* gWb    = (const float*)d_in[9];
  const float* gA     = (const float*)d_in[10];
  const float* gGateW = (const float*)d_in[11];
  const float* gGateb = (const float*)d_in[12];
  const float* WA1    = (const float*)d_in[13];
  const float* bA1    = (const float*)d_in[14];
  const float* WA2    = (const float*)d_in[15];
  const float* bA2    = (const float*)d_in[16];
  const float* WB1    = (const float*)d_in[17];
  const float* bB1    = (const float*)d_in[18];
  const float* WB2    = (const float*)d_in[19];
  const float* bB2    = (const float*)d_in[20];
  const float* Cv     = (const float*)d_in[21];
  const float* Wi1    = (const float*)d_in[22];
  const float* bi1    = (const float*)d_in[23];
  const float* Wi2    = (const float*)d_in[24];
  const float* bi2    = (const float*)d_in[25];

  float* base = (float*)d_ws;
  size_t off = 0;
  auto alloc = [&](size_t n) { float* p = base + off; off += n; return p; };
  float* h1a   = alloc((size_t)NB*N1S*DD);
  float* h1b   = alloc((size_t)NB*N1S*DD);
  float* h2a   = alloc((size_t)NB*N2S*DD);
  float* h2b   = alloc((size_t)NB*N2S*DD);
  float* hb1   = alloc((size_t)NB*N1S*DD);
  float* hAb1  = alloc((size_t)NB*N1S*DD);
  float* hb2   = alloc((size_t)NB*N2S*DD);
  float* hAb2  = alloc((size_t)NB*N2S*DD);
  float* e1    = alloc((size_t)NB*N1S*N1S);
  float* e2    = alloc((size_t)NB*N2S*N2S);
  float* m1    = alloc((size_t)NB*N1S);
  float* s1    = alloc((size_t)NB*N1S);
  float* m2    = alloc((size_t)NB*N2S);
  float* s2    = alloc((size_t)NB*N2S);
  float* pm2   = alloc((size_t)SCH*NB*N2S);
  float* ps2   = alloc((size_t)SCH*NB*N2S);
  float* U1A   = alloc((size_t)NT*NB*N1S*DD);
  float* U2A   = alloc((size_t)NT*NB*N2S*DD);
  float* U1B   = alloc((size_t)NT*NB*N1S*DD);
  float* U2B   = alloc((size_t)NT*NB*N2S*DD);
  float* retval= alloc(NB*NT);
  int*   counts= (int*)alloc(NB*NT*CSTR);
  int*   lists = (int*)alloc((size_t)NB*NT*LCAP);

  hipMemsetAsync(retval, 0, NB*NT*sizeof(float), stream);
  hipMemsetAsync(counts, 0, NB*NT*CSTR*sizeof(int), stream);

  // sparse list build (independent of GAT chain)
  k_build<<<dim3((NB*NT*N1S*N2S)/256), 256, 0, stream>>>(A_int, counts, lists);

  k_embed<<<dim3(NB*(N1S+N2S)), 128, 0, stream>>>(h1, h2, W_embed, h1a, h2a);

  float* c1 = h1a; float* o1 = h1b;
  float* c2 = h2a; float* o2 = h2b;
  for (int l = 0; l < 3; ++l) {
    const float* W  = gW + (size_t)l*DD*DD;
    const float* Wb = gWb + (size_t)l*DD;
    const float* A  = gA + (size_t)l*DD*DD;
    const float* Wg = gGateW + (size_t)l*2*DD;
    const float* bg = gGateb + l;
    k_gemm128<<<dim3(4, 144), 256, 0, stream>>>(c1, c2, 16, W, Wb, hb1, hb2);
    k_gemm128<<<dim3(4, 144), 256, 0, stream>>>(hb1, hb2, 16, A, nullptr, hAb1, hAb2);
    k_egemm<<<dim3(16, 18, NB), 256, 0, stream>>>(hAb2, hb2, e2, hAb1, hb1, e1);
    k_stats<<<dim3(9, SCH, NB), 256, 0, stream>>>(e2, adj2, pm2, ps2, e1, adj1, m1, s1);
    k_scomb<<<dim3(NB), 512, 0, stream>>>(pm2, ps2, m2, s2);
    k_hp<<<dim3(144, NB), 128, 0, stream>>>(e2, adj2, m2, s2, hb2, c2, o2,
                                            e1, adj1, m1, s1, hb1, c1, o1, Wg, bg);
    float* tmp;
    tmp = c1; c1 = o1; o1 = tmp;
    tmp = c2; c2 = o2; o2 = tmp;
  }

  // U1 = h1e @ W1_top (+b1); U2 = h2e @ W1_bot  — all 14 (t,mlp) in one launch
  k_ugemm<<<dim3(4, 144, 14), 256, 0, stream>>>(c1, c2, WA1, bA1, WB1, bB1,
                                                U1A, U2A, U1B, U2B);
  k_pair<<<dim3(32, NB*NT), 256, 0, stream>>>(U1A, U2A, U1B, U2B,
      WA2, bA2, WB2, bB2, dmv, Cv, lists, counts, retval);

  k_intercept<<<dim3(NB), 128, 0, stream>>>(c1, valid, Wi1, bi1, Wi2, bi2, retval,
                                            (float*)d_out);
}

// Round 13
// 484.985 us; speedup vs baseline: 1.8417x; 1.0079x over previous
//
#include <hip/hip_runtime.h>
#include <hip/hip_bf16.h>

// Problem constants
#define NB 8
#define N1S 64
#define N2S 512
#define DD 128
#define HH 128
#define NT 7
#define LCAP 4096   // per-(b,t) list capacity
#define CSTR 16     // counts[] stride in ints (64B line) to kill atomic contention
#define SCH 16      // row-chunks for set2 stats partial reduction

__device__ __constant__ float BCON[NT] = {1.159f,0.448f,0.927f,0.902f,0.349f,0.789f,0.198f};

// ---------------- embed: out[row,:] = x[row,:56] @ W[56,128] ----------------
__global__ __launch_bounds__(128) void k_embed(const float* __restrict__ x1,
                                               const float* __restrict__ x2,
                                               const float* __restrict__ W,
                                               float* __restrict__ o1,
                                               float* __restrict__ o2) {
  int row = blockIdx.x; int d = threadIdx.x;
  const float* x; float* out;
  if (row < NB*N1S) { x = x1 + (size_t)row*56;            out = o1 + (size_t)row*DD; }
  else              { x = x2 + (size_t)(row-NB*N1S)*56;   out = o2 + (size_t)(row-NB*N1S)*DD; }
  __shared__ float xs[64];
  if (d < 56) xs[d] = x[d];
  __syncthreads();
  float acc = 0.f;
  for (int k = 0; k < 56; ++k) acc += xs[k] * W[k*DD + d];
  out[d] = acc;
}

// ---- shared 64x64-tile fp32 GEMM core: C[64x64] = A[64x128] @ B[128x64] (+bias) ----
// 256 threads, 4x4 outputs/thread. A staged transposed so both operands are
// read via aligned ds_read_b128; Bs reads are 16-way broadcast (free).
__device__ __forceinline__ void gemm64_core(
    const float* __restrict__ A, const float* __restrict__ B,
    const float* __restrict__ bias, float* __restrict__ C,
    int row0, int j0)
{
  __shared__ float AsT[32][68];   // [k][row], 68 keeps float4 alignment, shifts banks
  __shared__ float Bs[32][68];    // [k][col]
  int t = threadIdx.x;
  int lr = t >> 2, lc = t & 3;    // A loader: row (0..63), k-octet (0..3)
  int kr = t >> 3, cc = t & 7;    // B loader: k-row (0..31), col-octet (0..7)
  int tm = t & 15, tn = t >> 4;   // compute: row-quad (0..15), col-quad (0..15)
  float acc[4][4] = {};
  for (int kc = 0; kc < 128; kc += 32) {
    float4 a0 = *(const float4*)(A + (size_t)(row0+lr)*128 + kc + lc*8);
    float4 a1 = *(const float4*)(A + (size_t)(row0+lr)*128 + kc + lc*8 + 4);
    float4 b0 = *(const float4*)(B + (size_t)(kc+kr)*128 + j0 + cc*8);
    float4 b1 = *(const float4*)(B + (size_t)(kc+kr)*128 + j0 + cc*8 + 4);
    __syncthreads();               // previous iteration's reads done before overwrite
    AsT[lc*8+0][lr] = a0.x; AsT[lc*8+1][lr] = a0.y;
    AsT[lc*8+2][lr] = a0.z; AsT[lc*8+3][lr] = a0.w;
    AsT[lc*8+4][lr] = a1.x; AsT[lc*8+5][lr] = a1.y;
    AsT[lc*8+6][lr] = a1.z; AsT[lc*8+7][lr] = a1.w;
    *(float4*)&Bs[kr][cc*8]   = b0;
    *(float4*)&Bs[kr][cc*8+4] = b1;
    __syncthreads();
    #pragma unroll
    for (int kk = 0; kk < 32; ++kk) {
      float4 a4 = *(const float4*)&AsT[kk][tm*4];
      float4 b4 = *(const float4*)&Bs[kk][tn*4];
      acc[0][0] += a4.x*b4.x; acc[0][1] += a4.x*b4.y; acc[0][2] += a4.x*b4.z; acc[0][3] += a4.x*b4.w;
      acc[1][0] += a4.y*b4.x; acc[1][1] += a4.y*b4.y; acc[1][2] += a4.y*b4.z; acc[1][3] += a4.y*b4.w;
      acc[2][0] += a4.z*b4.x; acc[2][1] += a4.z*b4.y; acc[2][2] += a4.z*b4.z; acc[2][3] += a4.z*b4.w;
      acc[3][0] += a4.w*b4.x; acc[3][1] += a4.w*b4.y; acc[3][2] += a4.w*b4.z; acc[3][3] += a4.w*b4.w;
    }
  }
  float4 bv = make_float4(0.f,0.f,0.f,0.f);
  if (bias) bv = *(const float4*)(bias + j0 + tn*4);
  #pragma unroll
  for (int i = 0; i < 4; ++i) {
    float4 o = make_float4(acc[i][0]+bv.x, acc[i][1]+bv.y, acc[i][2]+bv.z, acc[i][3]+bv.w);
    *(float4*)(C + (size_t)(row0 + tm*4 + i)*128 + j0 + tn*4) = o;
  }
}

// ---- tiled GEMM  C = A @ B (+bias), K=128, two row-sources in one launch ----
// grid (2, split + M2/64): 64-row tiles, 64-col tiles.
__global__ __launch_bounds__(256) void k_gemm128(
    const float* __restrict__ A1, const float* __restrict__ A2, int split,
    const float* __restrict__ Bw, const float* __restrict__ bias,
    float* __restrict__ C1, float* __restrict__ C2)
{
  int yb = blockIdx.y;
  const float* A; float* C; int row0;
  if (yb < split) { A = A1; C = C1; row0 = yb*64; }
  else            { A = A2; C = C2; row0 = (yb-split)*64; }
  gemm64_core(A, Bw, bias, C, row0, blockIdx.x*64);
}

// ---- U-precompute: all 14 (type,mlp) first-layer GEMMs in one launch ----
// grid (2, 72, 14): y<8 -> c1 rows (top W1 half, bias folded), else c2 rows
// (bottom W1 half, no bias). z<7 -> A-MLP type z, else B-MLP type z-7.
__global__ __launch_bounds__(256) void k_ugemm(
    const float* __restrict__ c1, const float* __restrict__ c2,
    const float* __restrict__ WA1, const float* __restrict__ bA1,
    const float* __restrict__ WB1, const float* __restrict__ bB1,
    float* __restrict__ U1A, float* __restrict__ U2A,
    float* __restrict__ U1B, float* __restrict__ U2B)
{
  int z = blockIdx.z;
  int t7 = (z < 7) ? z : z - 7;
  const float* W1 = (z < 7 ? WA1 : WB1) + (size_t)t7*2*DD*HH;
  int yb = blockIdx.y;
  const float* A; float* C; int row0; const float* bias;
  if (yb < 8) {
    A = c1; row0 = yb*64;
    C = (z < 7 ? U1A : U1B) + (size_t)t7*NB*N1S*DD;
    bias = (z < 7 ? bA1 : bB1) + t7*HH;
  } else {
    A = c2; row0 = (yb-8)*64;
    C = (z < 7 ? U2A : U2B) + (size_t)t7*NB*N2S*DD;
    W1 += DD*HH;
    bias = nullptr;
  }
  gemm64_core(A, W1, bias, C, row0, blockIdx.x*64);
}

// ---- esym[b,i,j] = hA[i].h[j] + h[i].hA[j]  (symmetric; both sets) ----
__global__ __launch_bounds__(256) void k_egemm(
    const float* __restrict__ hA2, const float* __restrict__ h2v, float* __restrict__ e2,
    const float* __restrict__ hA1, const float* __restrict__ h1v, float* __restrict__ e1)
{
  int b = blockIdx.z;
  int N, i0, j0; const float *Ap, *Hp; float* ep;
  if (blockIdx.y < 16) {
    N = N2S; i0 = blockIdx.y*32; j0 = blockIdx.x*32;
    Ap = hA2 + (size_t)b*N*DD; Hp = h2v + (size_t)b*N*DD; ep = e2 + (size_t)b*N*N;
  } else {
    if (blockIdx.x >= 2) return;
    N = N1S; i0 = (blockIdx.y-16)*32; j0 = blockIdx.x*32;
    Ap = hA1 + (size_t)b*N*DD; Hp = h1v + (size_t)b*N*DD; ep = e1 + (size_t)b*N*N;
  }
  __shared__ float As1[32][36], Hs1[32][36], As2T[32][36], Hs2T[32][36];
  int t = threadIdx.x;
  int lr = t >> 3, lc = t & 7;
  int ti = t >> 3, tj4 = t & 7;
  float acc[4] = {0.f,0.f,0.f,0.f};
  for (int kc = 0; kc < DD; kc += 32) {
    float4 a1 = *(const float4*)(Ap + (size_t)(i0+lr)*DD + kc + lc*4);
    float4 hi = *(const float4*)(Hp + (size_t)(i0+lr)*DD + kc + lc*4);
    float4 a2 = *(const float4*)(Ap + (size_t)(j0+lr)*DD + kc + lc*4);
    float4 hj = *(const float4*)(Hp + (size_t)(j0+lr)*DD + kc + lc*4);
    *(float4*)&As1[lr][lc*4] = a1;
    *(float4*)&Hs1[lr][lc*4] = hi;
    As2T[lc*4+0][lr] = a2.x; As2T[lc*4+1][lr] = a2.y; As2T[lc*4+2][lr] = a2.z; As2T[lc*4+3][lr] = a2.w;
    Hs2T[lc*4+0][lr] = hj.x; Hs2T[lc*4+1][lr] = hj.y; Hs2T[lc*4+2][lr] = hj.z; Hs2T[lc*4+3][lr] = hj.w;
    __syncthreads();
    for (int kk = 0; kk < 32; ++kk) {
      float a  = As1[ti][kk];
      float hv = Hs1[ti][kk];
      float4 h4 = *(const float4*)&Hs2T[kk][tj4*4];
      float4 a4 = *(const float4*)&As2T[kk][tj4*4];
      acc[0] += a*h4.x + hv*a4.x;
      acc[1] += a*h4.y + hv*a4.y;
      acc[2] += a*h4.z + hv*a4.z;
      acc[3] += a*h4.w + hv*a4.w;
    }
    __syncthreads();
  }
  *(float4*)(ep + (size_t)(i0+ti)*N + j0 + tj4*4) = make_float4(acc[0],acc[1],acc[2],acc[3]);
}

// ---- stats phase 1: per-row-chunk partial (m,s) of masked esym columns ----
__global__ __launch_bounds__(256) void k_stats(
    const float* __restrict__ e2, const float* __restrict__ adj2,
    float* __restrict__ pm2, float* __restrict__ ps2,
    const float* __restrict__ e1, const float* __restrict__ adj1,
    float* __restrict__ m1, float* __restrict__ s1v)
{
  int b = blockIdx.z;
  int tj = threadIdx.x & 63, ti = threadIdx.x >> 6;
  __shared__ float lm[4][64], ls[4][64];
  if (blockIdx.x < 8) {
    const int N = N2S;
    int j = blockIdx.x*64 + tj;
    const float* ep = e2 + (size_t)b*N*N;
    const float* ap = adj2 + (size_t)b*N*N;
    int ibase = blockIdx.y*32 + ti;
    float v[8];
    #pragma unroll
    for (int r = 0; r < 8; ++r) {
      int i = ibase + r*4;
      float av = ap[(size_t)i*N + j];
      float evv = ep[(size_t)i*N + j];
      v[r] = (av > 0.f) ? evv : -9e15f;
    }
    float m = v[0];
    #pragma unroll
    for (int r = 1; r < 8; ++r) m = fmaxf(m, v[r]);
    float s = 0.f;
    #pragma unroll
    for (int r = 0; r < 8; ++r) s += __expf(v[r] - m);
    lm[ti][tj] = m; ls[ti][tj] = s;
    __syncthreads();
    if (ti == 0) {
      float M = fmaxf(fmaxf(lm[0][tj], lm[1][tj]), fmaxf(lm[2][tj], lm[3][tj]));
      float S = ls[0][tj]*__expf(lm[0][tj]-M) + ls[1][tj]*__expf(lm[1][tj]-M)
              + ls[2][tj]*__expf(lm[2][tj]-M) + ls[3][tj]*__expf(lm[3][tj]-M);
      size_t o = ((size_t)blockIdx.y*NB + b)*N2S + j;
      pm2[o] = M; ps2[o] = S;
    }
  } else {
    if (blockIdx.y != 0) return;
    const int N = N1S;
    int j = tj;
    const float* ep = e1 + (size_t)b*N*N;
    const float* ap = adj1 + (size_t)b*N*N;
    float v[16];
    #pragma unroll
    for (int r = 0; r < 16; ++r) {
      int i = ti + r*4;
      float av = ap[(size_t)i*N + j];
      float evv = ep[(size_t)i*N + j];
      v[r] = (av > 0.f) ? evv : -9e15f;
    }
    float m = v[0];
    #pragma unroll
    for (int r = 1; r < 16; ++r) m = fmaxf(m, v[r]);
    float s = 0.f;
    #pragma unroll
    for (int r = 0; r < 16; ++r) s += __expf(v[r] - m);
    lm[ti][tj] = m; ls[ti][tj] = s;
    __syncthreads();
    if (ti == 0) {
      float M = fmaxf(fmaxf(lm[0][tj], lm[1][tj]), fmaxf(lm[2][tj], lm[3][tj]));
      float S = ls[0][tj]*__expf(lm[0][tj]-M) + ls[1][tj]*__expf(lm[1][tj]-M)
              + ls[2][tj]*__expf(lm[2][tj]-M) + ls[3][tj]*__expf(lm[3][tj]-M);
      m1[(size_t)b*N + j] = M;
      s1v[(size_t)b*N + j] = S;
    }
  }
}

// ---- stats phase 2: combine SCH partials per set2 column ----
__global__ __launch_bounds__(512) void k_scomb(const float* __restrict__ pm2,
                                               const float* __restrict__ ps2,
                                               float* __restrict__ m2,
                                               float* __restrict__ s2v) {
  int b = blockIdx.x; int j = threadIdx.x;  // 512 columns
  float m = -3.0e38f;
  #pragma unroll
  for (int c = 0; c < SCH; ++c) m = fmaxf(m, pm2[((size_t)c*NB + b)*N2S + j]);
  float s = 0.f;
  #pragma unroll
  for (int c = 0; c < SCH; ++c) {
    size_t o = ((size_t)c*NB + b)*N2S + j;
    s += ps2[o]*__expf(pm2[o] - m);
  }
  m2[(size_t)b*N2S + j] = m;
  s2v[(size_t)b*N2S + j] = s;
}

// ---- hp + gate + blend, both sets: grid (144, NB), 128 thr, 4 rows/block ----
__global__ __launch_bounds__(128) void k_hp(
    const float* __restrict__ e2, const float* __restrict__ adj2,
    const float* __restrict__ m2, const float* __restrict__ s2v,
    const float* __restrict__ hb2, const float* __restrict__ x2, float* __restrict__ o2,
    const float* __restrict__ e1, const float* __restrict__ adj1,
    const float* __restrict__ m1, const float* __restrict__ s1v,
    const float* __restrict__ hb1, const float* __restrict__ x1, float* __restrict__ o1,
    const float* __restrict__ Wg, const float* __restrict__ bg)
{
  int b = blockIdx.y; int d = threadIdx.x;
  int N, i0; const float *ep, *ap, *msb, *ssb, *hb, *x; float* out;
  if (blockIdx.x < 128) {
    N = N2S; i0 = blockIdx.x*4;
    ep = e2 + (size_t)b*N*N; ap = adj2 + (size_t)b*N*N;
    msb = m2 + (size_t)b*N;  ssb = s2v + (size_t)b*N;
    hb = hb2 + (size_t)b*N*DD; x = x2 + (size_t)b*N*DD; out = o2 + (size_t)b*N*DD;
  } else {
    N = N1S; i0 = (blockIdx.x-128)*4;
    ep = e1 + (size_t)b*N*N; ap = adj1 + (size_t)b*N*N;
    msb = m1 + (size_t)b*N;  ssb = s1v + (size_t)b*N;
    hb = hb1 + (size_t)b*N*DD; x = x1 + (size_t)b*N*DD; out = o1 + (size_t)b*N*DD;
  }
  __shared__ float ps[4][DD];
  __shared__ float wred[4][2];
  float hp[4] = {0.f,0.f,0.f,0.f};
  for (int j0 = 0; j0 < N; j0 += DD) {
    int j = j0 + d;
    if (j < N) {
      float mj = msb[j], sj = ssb[j];
      for (int r = 0; r < 4; ++r) {
        int i = i0 + r;
        float av = ap[(size_t)i*N + j];
        float p = 0.f;
        if (av > 0.f)
          p = __expf(ep[(size_t)i*N + j] - mj) / sj;
        ps[r][d] = p;
      }
    } else {
      for (int r = 0; r < 4; ++r) ps[r][d] = 0.f;
    }
    __syncthreads();
    int jmax = min(DD, N - j0);
    for (int jj = 0; jj < jmax; ++jj) {
      float hv = hb[(size_t)(j0+jj)*DD + d];
      hp[0] += ps[0][jj]*hv;
      hp[1] += ps[1][jj]*hv;
      hp[2] += ps[2][jj]*hv;
      hp[3] += ps[3][jj]*hv;
    }
    __syncthreads();
  }
  // gate: per-wave shfl reduce (one sync total for all 4 rows)
  float hpr[4], xv[4];
  for (int r = 0; r < 4; ++r) {
    int i = i0 + r;
    hpr[r] = fmaxf(hp[r], 0.f);
    xv[r] = x[(size_t)i*DD + d];
    float rv = xv[r]*Wg[d] + hpr[r]*Wg[DD + d];
    for (int off = 32; off; off >>= 1) rv += __shfl_xor(rv, off);
    if ((d & 63) == 0) wred[r][d >> 6] = rv;
  }
  __syncthreads();
  float bg0 = bg[0];
  for (int r = 0; r < 4; ++r) {
    int i = i0 + r;
    float coeff = 1.f/(1.f + __expf(-(wred[r][0] + wred[r][1] + bg0)));
    out[(size_t)i*DD + d] = coeff*xv[r] + (1.f - coeff)*hpr[r];
  }
}

// ------- build active (i1,i2) lists; LDS-aggregated -> ONE atomic per block -------
__global__ __launch_bounds__(256) void k_build(const float* __restrict__ A_int,
                                               int* __restrict__ counts,
                                               int* __restrict__ lists) {
  int idx = blockIdx.x*256 + threadIdx.x;
  bool active = (A_int[idx] != 0.f);
  unsigned long long mask = __ballot(active);
  int lane = threadIdx.x & 63;
  int w = threadIdx.x >> 6;
  int bt = idx >> 15;
  int before = __popcll(mask & ((1ull << lane) - 1ull));
  int n = __popcll(mask);
  __shared__ int wcnt[4];
  __shared__ int blockBase;
  if (lane == 0) wcnt[w] = n;
  __syncthreads();
  if (threadIdx.x == 0) {
    int total = wcnt[0] + wcnt[1] + wcnt[2] + wcnt[3];
    blockBase = total ? atomicAdd(&counts[bt*CSTR], total) : 0;
    int run = 0;
    for (int i = 0; i < 4; ++i) { int c = wcnt[i]; wcnt[i] = run; run += c; }
  }
  __syncthreads();
  if (active) {
    int pos = blockBase + wcnt[w] + before;
    if (pos < LCAP) lists[bt*LCAP + pos] = idx & 32767;  // (i1<<9)|i2
  }
}

// ------- sparse pair phase: hid = relu(U1[i1]+U2[i2]); sig(hid.W2+b2) -------
__global__ __launch_bounds__(256) void k_pair(
    const float* __restrict__ U1A, const float* __restrict__ U2A,
    const float* __restrict__ U1B, const float* __restrict__ U2B,
    const float* __restrict__ WA2, const float* __restrict__ bA2,
    const float* __restrict__ WB2, const float* __restrict__ bB2,
    const float* __restrict__ dmv, const float* __restrict__ Cv,
    const int* __restrict__ lists, const int* __restrict__ counts,
    float* __restrict__ retval)
{
  int bt = blockIdx.y; int b = bt / NT, t = bt % NT;
  int cnt = min(counts[bt*CSTR], LCAP);
  __shared__ __align__(16) float w2a[HH], w2b[HH];
  int tid = threadIdx.x;
  if (tid < HH) w2a[tid] = WA2[t*HH + tid];
  else          w2b[tid-HH] = WB2[t*HH + tid - HH];
  __syncthreads();
  int lane = tid & 63, w = tid >> 6;
  float bcv = BCON[t];
  float bcinv = 1.f/(3.f*bcv*bcv);
  float b2a = bA2[t], b2b = bB2[t], c = Cv[t];
  const float* u1a = U1A + (size_t)t*NB*N1S*DD + (size_t)b*N1S*DD;
  const float* u2a = U2A + (size_t)t*NB*N2S*DD + (size_t)b*N2S*DD;
  const float* u1b = U1B + (size_t)t*NB*N1S*DD + (size_t)b*N1S*DD;
  const float* u2b = U2B + (size_t)t*NB*N2S*DD + (size_t)b*N2S*DD;
  float2 wva = ((const float2*)w2a)[lane];
  float2 wvb = ((const float2*)w2b)[lane];
  float acc = 0.f;
  for (int p = blockIdx.x*4 + w; p < cnt; p += gridDim.x*4) {
    int id = lists[bt*LCAP + p];
    int i1 = id >> 9, i2 = id & 511;
    float2 a1 = ((const float2*)(u1a + (size_t)i1*DD))[lane];
    float2 a2 = ((const float2*)(u2a + (size_t)i2*DD))[lane];
    float2 b1 = ((const float2*)(u1b + (size_t)i1*DD))[lane];
    float2 b2 = ((const float2*)(u2b + (size_t)i2*DD))[lane];
    float pA = fmaxf(a1.x + a2.x, 0.f)*wva.x + fmaxf(a1.y + a2.y, 0.f)*wva.y;
    float pB = fmaxf(b1.x + b2.x, 0.f)*wvb.x + fmaxf(b1.y + b2.y, 0.f)*wvb.y;
    for (int off = 32; off; off >>= 1) {
      pA += __shfl_xor(pA, off);
      pB += __shfl_xor(pB, off);
    }
    float Aval = 4.f/(1.f + __expf(-(pA + b2a)));
    float Bval = (2.f*bcinv)/(1.f + __expf(-(pB + b2b))) + bcinv;
    const float* dp = dmv + (((size_t)b*N1S + i1)*N2S + i2)*3;
    float dx = dp[0], dy = dp[1], dz = dp[2];
    float dm = sqrtf(dx*dx + dy*dy + dz*dz + 1e-10f);
    if (dm < 0.5f) dm = 1e10f;
    float diff = dm - c;
    float ev = Aval*(Bval*diff*diff - 1.f);
    if (lane == 0) acc += ev;
  }
  __shared__ float wsum[4];
  if (lane == 0) wsum[w] = acc;
  __syncthreads();
  if (tid == 0)
    atomicAdd(&retval[bt], wsum[0]+wsum[1]+wsum[2]+wsum[3]);
}

// ---------------- pooled intercept + final output ----------------
__global__ __launch_bounds__(128) void k_intercept(const float* __restrict__ h1e,
                                                   const float* __restrict__ valid,
                                                   const float* __restrict__ Wi1,
                                                   const float* __restrict__ bi1,
                                                   const float* __restrict__ Wi2,
                                                   const float* __restrict__ bi2,
                                                   const float* __restrict__ retval,
                                                   float* __restrict__ out) {
  int b = blockIdx.x; int d = threadIdx.x;
  __shared__ float pooled[DD], hid[DD], red[DD];
  float s = 0.f;
  for (int i = 0; i < N1S; ++i)
    s += h1e[((size_t)b*N1S + i)*DD + d] * valid[b*N1S + i];
  pooled[d] = s;
  __syncthreads();
  float a = bi1[d];
  for (int k = 0; k < DD; ++k) a += pooled[k]*Wi1[k*HH + d];
  hid[d] = fmaxf(a, 0.f);
  __syncthreads();
  red[d] = hid[d]*Wi2[d];
  __syncthreads();
  for (int s2 = 64; s2 > 0; s2 >>= 1) {
    if (d < s2) red[d] += red[d + s2];
    __syncthreads();
  }
  float inter = 4.f/(1.f + __expf(-(red[0] + bi2[0])));
  if (d < NT) out[b*NT + d] = retval[b*NT + d] + inter/(float)NT;
}

extern "C" void kernel_launch(void* const* d_in, const int* in_sizes, int n_in,
                              void* d_out, int out_size, void* d_ws, size_t ws_size,
                              hipStream_t stream) {
  (void)in_sizes; (void)n_in; (void)out_size; (void)ws_size;
  const float* h1     = (const float*)d_in[0];
  const float* adj1   = (const float*)d_in[1];
  const float* h2     = (const float*)d_in[2];
  const float* adj2   = (const float*)d_in[3];
  const float* A_int  = (const float*)d_in[4];
  const float* dmv    = (const float*)d_in[5];
  const float* valid  = (const float*)d_in[6];
  const float* W_embed= (const float*)d_in[7];
  const float* gW     = (const float*)d_in[8];
  const float* gWb    = (const float*)d_in[9];
  const float* gA     = (const float*)d_in[10];
  const float* gGateW = (const float*)d_in[11];
  const float* gGateb = (const float*)d_in[12];
  const float* WA1    = (const float*)d_in[13];
  const float* bA1    = (const float*)d_in[14];
  const float* WA2    = (const float*)d_in[15];
  const float* bA2    = (const float*)d_in[16];
  const float* WB1    = (const float*)d_in[17];
  const float* bB1    = (const float*)d_in[18];
  const float* WB2    = (const float*)d_in[19];
  const float* bB2    = (const float*)d_in[20];
  const float* Cv     = (const float*)d_in[21];
  const float* Wi1    = (const float*)d_in[22];
  const float* bi1    = (const float*)d_in[23];
  const float* Wi2    = (const float*)d_in[24];
  const float* bi2    = (const float*)d_in[25];

  float* base = (float*)d_ws;
  size_t off = 0;
  auto alloc = [&](size_t n) { float* p = base + off; off += n; return p; };
  float* h1a   = alloc((size_t)NB*N1S*DD);
  float* h1b   = alloc((size_t)NB*N1S*DD);
  float* h2a   = alloc((size_t)NB*N2S*DD);
  float* h2b   = alloc((size_t)NB*N2S*DD);
  float* hb1   = alloc((size_t)NB*N1S*DD);
  float* hAb1  = alloc((size_t)NB*N1S*DD);
  float* hb2   = alloc((size_t)NB*N2S*DD);
  float* hAb2  = alloc((size_t)NB*N2S*DD);
  float* e1    = alloc((size_t)NB*N1S*N1S);
  float* e2    = alloc((size_t)NB*N2S*N2S);
  float* m1    = alloc((size_t)NB*N1S);
  float* s1    = alloc((size_t)NB*N1S);
  float* m2    = alloc((size_t)NB*N2S);
  float* s2    = alloc((size_t)NB*N2S);
  float* pm2   = alloc((size_t)SCH*NB*N2S);
  float* ps2   = alloc((size_t)SCH*NB*N2S);
  float* U1A   = alloc((size_t)NT*NB*N1S*DD);
  float* U2A   = alloc((size_t)NT*NB*N2S*DD);
  float* U1B   = alloc((size_t)NT*NB*N1S*DD);
  float* U2B   = alloc((size_t)NT*NB*N2S*DD);
  float* retval= alloc(NB*NT);
  int*   counts= (int*)alloc(NB*NT*CSTR);
  int*   lists = (int*)alloc((size_t)NB*NT*LCAP);

  hipMemsetAsync(retval, 0, NB*NT*sizeof(float), stream);
  hipMemsetAsync(counts, 0, NB*NT*CSTR*sizeof(int), stream);

  // sparse list build (independent of GAT chain)
  k_build<<<dim3((NB*NT*N1S*N2S)/256), 256, 0, stream>>>(A_int, counts, lists);

  k_embed<<<dim3(NB*(N1S+N2S)), 128, 0, stream>>>(h1, h2, W_embed, h1a, h2a);

  float* c1 = h1a; float* o1 = h1b;
  float* c2 = h2a; float* o2 = h2b;
  for (int l = 0; l < 3; ++l) {
    const float* W  = gW + (size_t)l*DD*DD;
    const float* Wb = gWb + (size_t)l*DD;
    const float* A  = gA + (size_t)l*DD*DD;
    const float* Wg = gGateW + (size_t)l*2*DD;
    const float* bg = gGateb + l;
    k_gemm128<<<dim3(2, 72), 256, 0, stream>>>(c1, c2, 8, W, Wb, hb1, hb2);
    k_gemm128<<<dim3(2, 72), 256, 0, stream>>>(hb1, hb2, 8, A, nullptr, hAb1, hAb2);
    k_egemm<<<dim3(16, 18, NB), 256, 0, stream>>>(hAb2, hb2, e2, hAb1, hb1, e1);
    k_stats<<<dim3(9, SCH, NB), 256, 0, stream>>>(e2, adj2, pm2, ps2, e1, adj1, m1, s1);
    k_scomb<<<dim3(NB), 512, 0, stream>>>(pm2, ps2, m2, s2);
    k_hp<<<dim3(144, NB), 128, 0, stream>>>(e2, adj2, m2, s2, hb2, c2, o2,
                                            e1, adj1, m1, s1, hb1, c1, o1, Wg, bg);
    float* tmp;
    tmp = c1; c1 = o1; o1 = tmp;
    tmp = c2; c2 = o2; o2 = tmp;
  }

  // U1 = h1e @ W1_top (+b1); U2 = h2e @ W1_bot  — all 14 (t,mlp) in one launch
  k_ugemm<<<dim3(2, 72, 14), 256, 0, stream>>>(c1, c2, WA1, bA1, WB1, bB1,
                                               U1A, U2A, U1B, U2B);
  k_pair<<<dim3(32, NB*NT), 256, 0, stream>>>(U1A, U2A, U1B, U2B,
      WA2, bA2, WB2, bB2, dmv, Cv, lists, counts, retval);

  k_intercept<<<dim3(NB), 128, 0, stream>>>(c1, valid, Wi1, bi1, Wi2, bi2, retval,
                                            (float*)d_out);
}